// Round 1
// baseline (796.704 us; speedup 1.0000x reference)
//
#include <hip/hip_runtime.h>
#include <hip/hip_bf16.h>
#include <cstdint>

// GraphSAGE 2-layer, fp32.
//  layer: out = mean_agg(x) @ W_l + b + x @ W_r   (layer1 + relu, layer2 plain)
// Plan: build CSR once (hist -> scan -> scatter), reuse for both aggregations.

#define NNODES_DEFAULT 100000

// ---------------- edge dtype detection ----------------
__global__ void detect_i64(const void* ei, int n_nodes, int* flag) {
    const long long* p = (const long long*)ei;
    int ok = 1;
    for (int i = 0; i < 8; ++i) {
        long long v = p[i];
        if (v < 0 || v >= n_nodes) ok = 0;
    }
    *flag = ok;
}

__device__ __forceinline__ int edge_val(const int* ei32, const long long* ei64,
                                        int is64, size_t idx) {
    return is64 ? (int)ei64[idx] : ei32[idx];
}

// ---------------- CSR build ----------------
__global__ void hist_kernel(const int* ei32, const long long* ei64, const int* flag,
                            int E, int* off) {
    int is64 = *flag;
    int e = blockIdx.x * blockDim.x + threadIdx.x;
    if (e < E) {
        int d = edge_val(ei32, ei64, is64, (size_t)E + e);
        atomicAdd(&off[d + 1], 1);
    }
}

// inclusive scan of a[0..n) in chunks of 2048, block = 256 threads x 8 elems
__global__ __launch_bounds__(256) void scan_block(int* a, int n, int* sums) {
    int b = blockIdx.x;
    int t = threadIdx.x;
    int base = b * 2048 + t * 8;
    int v[8];
    int s = 0;
#pragma unroll
    for (int i = 0; i < 8; ++i) {
        int x = (base + i < n) ? a[base + i] : 0;
        s += x;
        v[i] = s;
    }
    __shared__ int tot[256];
    tot[t] = s;
    __syncthreads();
    for (int o = 1; o < 256; o <<= 1) {
        int x = (t >= o) ? tot[t - o] : 0;
        __syncthreads();
        if (t >= o) tot[t] += x;
        __syncthreads();
    }
    int excl = (t == 0) ? 0 : tot[t - 1];
#pragma unroll
    for (int i = 0; i < 8; ++i)
        if (base + i < n) a[base + i] = v[i] + excl;
    if (t == 255 && sums) sums[b] = tot[255];
}

__global__ void scan_sums(int* sums, int nb) {
    if (threadIdx.x == 0 && blockIdx.x == 0) {
        int run = 0;
        for (int i = 0; i < nb; ++i) {
            int v = sums[i];
            sums[i] = run;
            run += v;
        }
    }
}

__global__ __launch_bounds__(256) void scan_add(int* a, int n, const int* sums) {
    int b = blockIdx.x;
    int add = sums[b];
    int base = b * 2048;
    for (int i = threadIdx.x; i < 2048; i += 256) {
        int idx = base + i;
        if (idx < n) a[idx] += add;
    }
}

__global__ void scatter_kernel(const int* ei32, const long long* ei64, const int* flag,
                               int E, const int* off, int* pos, int* csr) {
    int is64 = *flag;
    int e = blockIdx.x * blockDim.x + threadIdx.x;
    if (e < E) {
        int s = edge_val(ei32, ei64, is64, (size_t)e);
        int d = edge_val(ei32, ei64, is64, (size_t)E + e);
        int slot = atomicAdd(&pos[d], 1);
        csr[off[d] + slot] = s;
    }
}

// ---------------- mean aggregation ----------------
// one wave per node; lane l owns feature dims (2l, 2l+1)
__global__ __launch_bounds__(256) void agg_mean(const float* __restrict__ X,
                                                const int* __restrict__ off,
                                                const int* __restrict__ csr,
                                                float* __restrict__ out, int n_nodes) {
    int node = blockIdx.x * 4 + (threadIdx.x >> 6);
    if (node >= n_nodes) return;
    int lane = threadIdx.x & 63;
    int s0 = off[node];
    int s1 = off[node + 1];
    float ax = 0.f, ay = 0.f;
    for (int j = s0; j < s1; ++j) {
        int s = csr[j];
        const float2 v = ((const float2*)(X + (size_t)s * 128))[lane];
        ax += v.x;
        ay += v.y;
    }
    float inv = (s1 > s0) ? 1.0f / (float)(s1 - s0) : 0.0f;
    float2 r;
    r.x = ax * inv;
    r.y = ay * inv;
    ((float2*)(out + (size_t)node * 128))[lane] = r;
}

// ---------------- fused SAGE linear: out = A@Wl + X@Wr + b (opt relu) ----------------
// K = 128 fixed. 32 rows/tile staged in LDS; thread computes RPT rows x 1 col.
template <int NCOL, bool RELU>
__global__ __launch_bounds__(256) void sage_lin(const float* __restrict__ A,
                                                const float* __restrict__ Xr,
                                                const float* __restrict__ Wl,
                                                const float* __restrict__ Wr,
                                                const float* __restrict__ bias,
                                                float* __restrict__ out, int nrows) {
    __shared__ __align__(16) float sA[32][128];
    __shared__ __align__(16) float sX[32][128];
    const int row0 = blockIdx.x * 32;
    const int t = threadIdx.x;

    // stage 32 rows of A and X (float4 each)
    for (int i = t; i < 32 * 32; i += 256) {
        int r = i >> 5, c = i & 31;
        int row = row0 + r;
        float4 va, vx;
        if (row < nrows) {
            va = ((const float4*)(A + (size_t)row * 128))[c];
            vx = ((const float4*)(Xr + (size_t)row * 128))[c];
        } else {
            va = make_float4(0.f, 0.f, 0.f, 0.f);
            vx = va;
        }
        ((float4*)(&sA[r][0]))[c] = va;
        ((float4*)(&sX[r][0]))[c] = vx;
    }
    __syncthreads();

    constexpr int G = 256 / NCOL;   // row groups per tile pass
    constexpr int RPT = 32 / G;     // rows per thread
    const int c = t % NCOL;
    const int rg = t / NCOL;

    float acc[RPT];
#pragma unroll
    for (int r = 0; r < RPT; ++r) acc[r] = 0.f;

    for (int k4 = 0; k4 < 32; ++k4) {
        float wl[4], wr[4];
#pragma unroll
        for (int j = 0; j < 4; ++j) {
            wl[j] = Wl[(k4 * 4 + j) * NCOL + c];
            wr[j] = Wr[(k4 * 4 + j) * NCOL + c];
        }
#pragma unroll
        for (int r = 0; r < RPT; ++r) {
            int row = rg + r * G;
            float4 a4 = *((const float4*)&sA[row][k4 * 4]);
            float4 x4 = *((const float4*)&sX[row][k4 * 4]);
            float s = acc[r];
            s = fmaf(a4.x, wl[0], s);
            s = fmaf(a4.y, wl[1], s);
            s = fmaf(a4.z, wl[2], s);
            s = fmaf(a4.w, wl[3], s);
            s = fmaf(x4.x, wr[0], s);
            s = fmaf(x4.y, wr[1], s);
            s = fmaf(x4.z, wr[2], s);
            s = fmaf(x4.w, wr[3], s);
            acc[r] = s;
        }
    }
    float bb = bias[c];
#pragma unroll
    for (int r = 0; r < RPT; ++r) {
        int row = row0 + rg + r * G;
        if (row < nrows) {
            float v = acc[r] + bb;
            if (RELU) v = fmaxf(v, 0.f);
            out[(size_t)row * NCOL + c] = v;
        }
    }
}

extern "C" void kernel_launch(void* const* d_in, const int* in_sizes, int n_in,
                              void* d_out, int out_size, void* d_ws, size_t ws_size,
                              hipStream_t stream) {
    const float* x    = (const float*)d_in[0];
    const float* W1_l = (const float*)d_in[1];
    const float* b1   = (const float*)d_in[2];
    const float* W1_r = (const float*)d_in[3];
    const float* W2_l = (const float*)d_in[4];
    const float* b2   = (const float*)d_in[5];
    const float* W2_r = (const float*)d_in[6];
    const void*  ei   = d_in[7];
    float* out = (float*)d_out;

    const int N = in_sizes[0] / 128;      // 100000
    const int E = in_sizes[7] / 2;        // 1600000

    // workspace layout
    uintptr_t base = (uintptr_t)d_ws;
    int* flag = (int*)base;               // 1 int
    int* sums = (int*)(base + 64);        // up to 112 ints
    int* off  = (int*)(base + 512);       // N+1
    int* pos  = off + (N + 1);            // N
    int* csr  = pos + N;                  // E
    uintptr_t fbase = ((uintptr_t)(csr + E) + 255) & ~(uintptr_t)255;
    float* meanbuf = (float*)fbase;             // N*128
    float* hbuf    = meanbuf + (size_t)N * 128; // N*128

    const int* ei32 = (const int*)ei;
    const long long* ei64 = (const long long*)ei;

    // zero off + pos (contiguous)
    hipMemsetAsync(off, 0, sizeof(int) * (size_t)(2 * N + 1), stream);

    detect_i64<<<1, 1, 0, stream>>>(ei, N, flag);

    int eblocks = (E + 255) / 256;
    hist_kernel<<<eblocks, 256, 0, stream>>>(ei32, ei64, flag, E, off);

    // inclusive scan over off[1..N]
    int NB = (N + 2047) / 2048;
    scan_block<<<NB, 256, 0, stream>>>(off + 1, N, sums);
    scan_sums<<<1, 64, 0, stream>>>(sums, NB);
    scan_add<<<NB, 256, 0, stream>>>(off + 1, N, sums);

    scatter_kernel<<<eblocks, 256, 0, stream>>>(ei32, ei64, flag, E, off, pos, csr);

    int ablocks = (N + 3) / 4;
    agg_mean<<<ablocks, 256, 0, stream>>>(x, off, csr, meanbuf, N);

    int gblocks = (N + 31) / 32;
    sage_lin<128, true><<<gblocks, 256, 0, stream>>>(meanbuf, x, W1_l, W1_r, b1, hbuf, N);

    agg_mean<<<ablocks, 256, 0, stream>>>(hbuf, off, csr, meanbuf, N);

    sage_lin<64, false><<<gblocks, 256, 0, stream>>>(meanbuf, hbuf, W2_l, W2_r, b2, out, N);
}

// Round 2
// 650.779 us; speedup vs baseline: 1.2242x; 1.2242x over previous
//
#include <hip/hip_runtime.h>
#include <hip/hip_bf16.h>
#include <cstdint>

// GraphSAGE 2-layer, fp32.
// Layer1: h   = relu(mean_agg(x) @ W1_l + b1 + x @ W1_r)
// Layer2: out = mean_agg(h @ W2_l) + h @ W2_r + b2        (agg commutes w/ linear)
// CSR built once (hist -> scan -> scatter), reused for both aggregations.

// ---------------- edge dtype detection ----------------
__global__ void detect_i64(const void* ei, int n_nodes, int* flag) {
    const long long* p = (const long long*)ei;
    int ok = 1;
    for (int i = 0; i < 8; ++i) {
        long long v = p[i];
        if (v < 0 || v >= n_nodes) ok = 0;
    }
    *flag = ok;
}

__device__ __forceinline__ int edge_val(const int* ei32, const long long* ei64,
                                        int is64, size_t idx) {
    return is64 ? (int)ei64[idx] : ei32[idx];
}

// ---------------- CSR build ----------------
__global__ void hist_kernel(const int* ei32, const long long* ei64, const int* flag,
                            int E, int* off) {
    int is64 = *flag;
    int e = blockIdx.x * blockDim.x + threadIdx.x;
    if (e < E) {
        int d = edge_val(ei32, ei64, is64, (size_t)E + e);
        atomicAdd(&off[d + 1], 1);
    }
}

__global__ __launch_bounds__(256) void scan_block(int* a, int n, int* sums) {
    int b = blockIdx.x;
    int t = threadIdx.x;
    int base = b * 2048 + t * 8;
    int v[8];
    int s = 0;
#pragma unroll
    for (int i = 0; i < 8; ++i) {
        int x = (base + i < n) ? a[base + i] : 0;
        s += x;
        v[i] = s;
    }
    __shared__ int tot[256];
    tot[t] = s;
    __syncthreads();
    for (int o = 1; o < 256; o <<= 1) {
        int x = (t >= o) ? tot[t - o] : 0;
        __syncthreads();
        if (t >= o) tot[t] += x;
        __syncthreads();
    }
    int excl = (t == 0) ? 0 : tot[t - 1];
#pragma unroll
    for (int i = 0; i < 8; ++i)
        if (base + i < n) a[base + i] = v[i] + excl;
    if (t == 255 && sums) sums[b] = tot[255];
}

__global__ void scan_sums(int* sums, int nb) {
    if (threadIdx.x == 0 && blockIdx.x == 0) {
        int run = 0;
        for (int i = 0; i < nb; ++i) {
            int v = sums[i];
            sums[i] = run;
            run += v;
        }
    }
}

__global__ __launch_bounds__(256) void scan_add(int* a, int n, const int* sums) {
    int b = blockIdx.x;
    int add = sums[b];
    int base = b * 2048;
    for (int i = threadIdx.x; i < 2048; i += 256) {
        int idx = base + i;
        if (idx < n) a[idx] += add;
    }
}

__global__ void scatter_kernel(const int* ei32, const long long* ei64, const int* flag,
                               int E, const int* off, int* pos, int* csr) {
    int is64 = *flag;
    int e = blockIdx.x * blockDim.x + threadIdx.x;
    if (e < E) {
        int s = edge_val(ei32, ei64, is64, (size_t)e);
        int d = edge_val(ei32, ei64, is64, (size_t)E + e);
        int slot = atomicAdd(&pos[d], 1);
        csr[off[d] + slot] = s;
    }
}

// ---------------- mean aggregation, D=128 ----------------
// one wave per node; lane covers 2 edges x 32 float4 slots (1KB/load-instr).
// half = which edge of the pair, l32 = float4 slot (dims 4*l32..4*l32+3).
__global__ __launch_bounds__(256) void agg_mean128(const float* __restrict__ X,
                                                   const int* __restrict__ off,
                                                   const int* __restrict__ csr,
                                                   float* __restrict__ out, int n_nodes) {
    int node = blockIdx.x * 4 + (threadIdx.x >> 6);
    if (node >= n_nodes) return;
    int lane = threadIdx.x & 63;
    int half = lane >> 5;
    int l32 = lane & 31;
    int s0 = off[node], s1 = off[node + 1];
    float4 a0 = make_float4(0.f, 0.f, 0.f, 0.f);
    float4 a1 = make_float4(0.f, 0.f, 0.f, 0.f);
    int j = s0;
    // 4 edges / iter, 2KB in flight
    for (; j + 4 <= s1; j += 4) {
        int p = csr[j + half];
        int q = csr[j + 2 + half];
        float4 v0 = ((const float4*)(X + (size_t)p * 128))[l32];
        float4 v1 = ((const float4*)(X + (size_t)q * 128))[l32];
        a0.x += v0.x; a0.y += v0.y; a0.z += v0.z; a0.w += v0.w;
        a1.x += v1.x; a1.y += v1.y; a1.z += v1.z; a1.w += v1.w;
    }
    if (j + 2 <= s1) {
        int p = csr[j + half];
        float4 v0 = ((const float4*)(X + (size_t)p * 128))[l32];
        a0.x += v0.x; a0.y += v0.y; a0.z += v0.z; a0.w += v0.w;
        j += 2;
    }
    if (j < s1 && half == 0) {
        int p = csr[j];
        float4 v0 = ((const float4*)(X + (size_t)p * 128))[l32];
        a0.x += v0.x; a0.y += v0.y; a0.z += v0.z; a0.w += v0.w;
    }
    float4 a;
    a.x = a0.x + a1.x; a.y = a0.y + a1.y; a.z = a0.z + a1.z; a.w = a0.w + a1.w;
    a.x += __shfl(a.x, lane ^ 32);
    a.y += __shfl(a.y, lane ^ 32);
    a.z += __shfl(a.z, lane ^ 32);
    a.w += __shfl(a.w, lane ^ 32);
    int deg = s1 - s0;
    float inv = (deg > 0) ? 1.0f / (float)deg : 0.0f;
    if (half == 0) {
        float4 r;
        r.x = a.x * inv; r.y = a.y * inv; r.z = a.z * inv; r.w = a.w * inv;
        ((float4*)(out + (size_t)node * 128))[l32] = r;
    }
}

// ---------------- mean aggregation, D=64, epilogue out = mean + Wadd ----------------
// lane covers 4 edges x 16 float4 slots. qd = edge of quad, l16 = float4 slot.
__global__ __launch_bounds__(256) void agg_mean64_ep(const float* __restrict__ Z,
                                                     const float* __restrict__ Wadd,
                                                     const int* __restrict__ off,
                                                     const int* __restrict__ csr,
                                                     float* __restrict__ out, int n_nodes) {
    int node = blockIdx.x * 4 + (threadIdx.x >> 6);
    if (node >= n_nodes) return;
    int lane = threadIdx.x & 63;
    int qd = lane >> 4;
    int l16 = lane & 15;
    int s0 = off[node], s1 = off[node + 1];
    float4 a0 = make_float4(0.f, 0.f, 0.f, 0.f);
    float4 a1 = make_float4(0.f, 0.f, 0.f, 0.f);
    int j = s0;
    // 8 edges / iter
    for (; j + 8 <= s1; j += 8) {
        int p = csr[j + qd];
        int q = csr[j + 4 + qd];
        float4 v0 = ((const float4*)(Z + (size_t)p * 64))[l16];
        float4 v1 = ((const float4*)(Z + (size_t)q * 64))[l16];
        a0.x += v0.x; a0.y += v0.y; a0.z += v0.z; a0.w += v0.w;
        a1.x += v1.x; a1.y += v1.y; a1.z += v1.z; a1.w += v1.w;
    }
    if (j + 4 <= s1) {
        int p = csr[j + qd];
        float4 v0 = ((const float4*)(Z + (size_t)p * 64))[l16];
        a0.x += v0.x; a0.y += v0.y; a0.z += v0.z; a0.w += v0.w;
        j += 4;
    }
    if (j < s1) {  // masked tail quad (1..3 edges)
        int jj = j + qd;
        int p = csr[(jj < s1) ? jj : (s1 - 1)];
        float w = (jj < s1) ? 1.0f : 0.0f;
        float4 v0 = ((const float4*)(Z + (size_t)p * 64))[l16];
        a0.x += v0.x * w; a0.y += v0.y * w; a0.z += v0.z * w; a0.w += v0.w * w;
    }
    float4 a;
    a.x = a0.x + a1.x; a.y = a0.y + a1.y; a.z = a0.z + a1.z; a.w = a0.w + a1.w;
    a.x += __shfl(a.x, lane ^ 32);
    a.y += __shfl(a.y, lane ^ 32);
    a.z += __shfl(a.z, lane ^ 32);
    a.w += __shfl(a.w, lane ^ 32);
    a.x += __shfl(a.x, lane ^ 16);
    a.y += __shfl(a.y, lane ^ 16);
    a.z += __shfl(a.z, lane ^ 16);
    a.w += __shfl(a.w, lane ^ 16);
    int deg = s1 - s0;
    float inv = (deg > 0) ? 1.0f / (float)deg : 0.0f;
    if (lane < 16) {
        float4 wv = ((const float4*)(Wadd + (size_t)node * 64))[l16];
        float4 r;
        r.x = a.x * inv + wv.x;
        r.y = a.y * inv + wv.y;
        r.z = a.z * inv + wv.z;
        r.w = a.w * inv + wv.w;
        ((float4*)(out + (size_t)node * 64))[l16] = r;
    }
}

// ---------------- fused SAGE linear: out = A@Wl + X@Wr + b (relu) ----------------
// K = 128 fixed. 32 rows/tile in LDS; thread computes RPT rows x 1 col.
template <int NCOL, bool RELU>
__global__ __launch_bounds__(256) void sage_lin(const float* __restrict__ A,
                                                const float* __restrict__ Xr,
                                                const float* __restrict__ Wl,
                                                const float* __restrict__ Wr,
                                                const float* __restrict__ bias,
                                                float* __restrict__ out, int nrows) {
    __shared__ __align__(16) float sA[32][128];
    __shared__ __align__(16) float sX[32][128];
    const int row0 = blockIdx.x * 32;
    const int t = threadIdx.x;

    for (int i = t; i < 32 * 32; i += 256) {
        int r = i >> 5, c = i & 31;
        int row = row0 + r;
        float4 va, vx;
        if (row < nrows) {
            va = ((const float4*)(A + (size_t)row * 128))[c];
            vx = ((const float4*)(Xr + (size_t)row * 128))[c];
        } else {
            va = make_float4(0.f, 0.f, 0.f, 0.f);
            vx = va;
        }
        ((float4*)(&sA[r][0]))[c] = va;
        ((float4*)(&sX[r][0]))[c] = vx;
    }
    __syncthreads();

    constexpr int G = 256 / NCOL;
    constexpr int RPT = 32 / G;
    const int c = t % NCOL;
    const int rg = t / NCOL;

    float acc[RPT];
#pragma unroll
    for (int r = 0; r < RPT; ++r) acc[r] = 0.f;

    for (int k4 = 0; k4 < 32; ++k4) {
        float wl[4], wr[4];
#pragma unroll
        for (int j = 0; j < 4; ++j) {
            wl[j] = Wl[(k4 * 4 + j) * NCOL + c];
            wr[j] = Wr[(k4 * 4 + j) * NCOL + c];
        }
#pragma unroll
        for (int r = 0; r < RPT; ++r) {
            int row = rg + r * G;
            float4 a4 = *((const float4*)&sA[row][k4 * 4]);
            float4 x4 = *((const float4*)&sX[row][k4 * 4]);
            float s = acc[r];
            s = fmaf(a4.x, wl[0], s);
            s = fmaf(a4.y, wl[1], s);
            s = fmaf(a4.z, wl[2], s);
            s = fmaf(a4.w, wl[3], s);
            s = fmaf(x4.x, wr[0], s);
            s = fmaf(x4.y, wr[1], s);
            s = fmaf(x4.z, wr[2], s);
            s = fmaf(x4.w, wr[3], s);
            acc[r] = s;
        }
    }
    float bb = bias[c];
#pragma unroll
    for (int r = 0; r < RPT; ++r) {
        int row = row0 + rg + r * G;
        if (row < nrows) {
            float v = acc[r] + bb;
            if (RELU) v = fmaxf(v, 0.f);
            out[(size_t)row * NCOL + c] = v;
        }
    }
}

// ---------------- dual GEMM: Z = H@Wl ; W_out = H@Wr + b  (NCOL=64) ----------------
__global__ __launch_bounds__(256) void dual_gemm64(const float* __restrict__ H,
                                                   const float* __restrict__ Wl,
                                                   const float* __restrict__ Wr,
                                                   const float* __restrict__ bias,
                                                   float* __restrict__ Z,
                                                   float* __restrict__ Wout, int nrows) {
    __shared__ __align__(16) float sH[32][128];
    const int row0 = blockIdx.x * 32;
    const int t = threadIdx.x;

    for (int i = t; i < 32 * 32; i += 256) {
        int r = i >> 5, c = i & 31;
        int row = row0 + r;
        float4 vh = make_float4(0.f, 0.f, 0.f, 0.f);
        if (row < nrows) vh = ((const float4*)(H + (size_t)row * 128))[c];
        ((float4*)(&sH[r][0]))[c] = vh;
    }
    __syncthreads();

    constexpr int G = 4;        // 256/64
    constexpr int RPT = 8;      // 32/G
    const int c = t & 63;
    const int rg = t >> 6;

    float accz[RPT], accw[RPT];
#pragma unroll
    for (int r = 0; r < RPT; ++r) { accz[r] = 0.f; accw[r] = 0.f; }

    for (int k4 = 0; k4 < 32; ++k4) {
        float wl[4], wr[4];
#pragma unroll
        for (int j = 0; j < 4; ++j) {
            wl[j] = Wl[(k4 * 4 + j) * 64 + c];
            wr[j] = Wr[(k4 * 4 + j) * 64 + c];
        }
#pragma unroll
        for (int r = 0; r < RPT; ++r) {
            int row = rg * RPT + r;
            float4 h4 = *((const float4*)&sH[row][k4 * 4]);
            float sz = accz[r], sw = accw[r];
            sz = fmaf(h4.x, wl[0], sz);
            sz = fmaf(h4.y, wl[1], sz);
            sz = fmaf(h4.z, wl[2], sz);
            sz = fmaf(h4.w, wl[3], sz);
            sw = fmaf(h4.x, wr[0], sw);
            sw = fmaf(h4.y, wr[1], sw);
            sw = fmaf(h4.z, wr[2], sw);
            sw = fmaf(h4.w, wr[3], sw);
            accz[r] = sz; accw[r] = sw;
        }
    }
    float bb = bias[c];
#pragma unroll
    for (int r = 0; r < RPT; ++r) {
        int row = row0 + rg * RPT + r;
        if (row < nrows) {
            Z[(size_t)row * 64 + c] = accz[r];
            Wout[(size_t)row * 64 + c] = accw[r] + bb;
        }
    }
}

extern "C" void kernel_launch(void* const* d_in, const int* in_sizes, int n_in,
                              void* d_out, int out_size, void* d_ws, size_t ws_size,
                              hipStream_t stream) {
    const float* x    = (const float*)d_in[0];
    const float* W1_l = (const float*)d_in[1];
    const float* b1   = (const float*)d_in[2];
    const float* W1_r = (const float*)d_in[3];
    const float* W2_l = (const float*)d_in[4];
    const float* b2   = (const float*)d_in[5];
    const float* W2_r = (const float*)d_in[6];
    const void*  ei   = d_in[7];
    float* out = (float*)d_out;

    const int N = in_sizes[0] / 128;      // 100000
    const int E = in_sizes[7] / 2;        // 1600000

    // workspace layout
    uintptr_t base = (uintptr_t)d_ws;
    int* flag = (int*)base;               // 1 int
    int* sums = (int*)(base + 64);        // up to 112 ints
    int* off  = (int*)(base + 512);       // N+1
    int* pos  = off + (N + 1);            // N
    int* csr  = pos + N;                  // E
    uintptr_t fbase = ((uintptr_t)(csr + E) + 255) & ~(uintptr_t)255;
    float* meanbuf = (float*)fbase;             // N*128 (later reused for z2|w2)
    float* hbuf    = meanbuf + (size_t)N * 128; // N*128
    float* z2 = meanbuf;                        // N*64 (meanbuf dead after sage_lin1)
    float* w2 = meanbuf + (size_t)N * 64;       // N*64

    const int* ei32 = (const int*)ei;
    const long long* ei64 = (const long long*)ei;

    hipMemsetAsync(off, 0, sizeof(int) * (size_t)(2 * N + 1), stream);

    detect_i64<<<1, 1, 0, stream>>>(ei, N, flag);

    int eblocks = (E + 255) / 256;
    hist_kernel<<<eblocks, 256, 0, stream>>>(ei32, ei64, flag, E, off);

    int NB = (N + 2047) / 2048;
    scan_block<<<NB, 256, 0, stream>>>(off + 1, N, sums);
    scan_sums<<<1, 64, 0, stream>>>(sums, NB);
    scan_add<<<NB, 256, 0, stream>>>(off + 1, N, sums);

    scatter_kernel<<<eblocks, 256, 0, stream>>>(ei32, ei64, flag, E, off, pos, csr);

    int ablocks = (N + 3) / 4;
    int gblocks = (N + 31) / 32;

    // layer 1: mean = agg(x); h = relu(mean@W1_l + x@W1_r + b1)
    agg_mean128<<<ablocks, 256, 0, stream>>>(x, off, csr, meanbuf, N);
    sage_lin<128, true><<<gblocks, 256, 0, stream>>>(meanbuf, x, W1_l, W1_r, b1, hbuf, N);

    // layer 2: z2 = h@W2_l; w2 = h@W2_r + b2; out = agg(z2) + w2
    dual_gemm64<<<gblocks, 256, 0, stream>>>(hbuf, W2_l, W2_r, b2, z2, w2, N);
    agg_mean64_ep<<<ablocks, 256, 0, stream>>>(z2, w2, off, csr, out, N);
}

// Round 3
// 463.044 us; speedup vs baseline: 1.7206x; 1.4054x over previous
//
#include <hip/hip_runtime.h>
#include <hip/hip_bf16.h>
#include <cstdint>

// GraphSAGE 2-layer, bf16 features + fp32 accumulate, MFMA GEMMs.
// Layer1: h   = relu([mean_agg(x) | x] @ [W1_l; W1_r] + b1)   (K=256 MFMA GEMM)
// Layer2: out = mean_agg(h @ W2_l) + h @ W2_r + b2            (agg commutes w/ linear)
// CSR built once (hist -> scan -> scatter), reused for both aggregations.

typedef __bf16 bf16x8 __attribute__((ext_vector_type(8)));
typedef float f32x4 __attribute__((ext_vector_type(4)));

__device__ __forceinline__ unsigned short f2bf(float f) {
    union { float f; unsigned int u; } v; v.f = f;
    unsigned int u = v.u;
    unsigned int r = ((u >> 16) & 1u) + 0x7fffu;
    return (unsigned short)((u + r) >> 16);
}
__device__ __forceinline__ float bflo(unsigned int u) {
    union { unsigned int u; float f; } v; v.u = u << 16; return v.f;
}
__device__ __forceinline__ float bfhi(unsigned int u) {
    union { unsigned int u; float f; } v; v.u = u & 0xffff0000u; return v.f;
}

// ---------------- edge dtype detection ----------------
__global__ void detect_i64(const void* ei, int n_nodes, int* flag) {
    const long long* p = (const long long*)ei;
    int ok = 1;
    for (int i = 0; i < 8; ++i) {
        long long v = p[i];
        if (v < 0 || v >= n_nodes) ok = 0;
    }
    *flag = ok;
}

__device__ __forceinline__ int edge_val(const int* ei32, const long long* ei64,
                                        int is64, size_t idx) {
    return is64 ? (int)ei64[idx] : ei32[idx];
}

// ---------------- CSR build ----------------
__global__ void hist_kernel(const int* ei32, const long long* ei64, const int* flag,
                            int E, int* off) {
    int is64 = *flag;
    int e = blockIdx.x * blockDim.x + threadIdx.x;
    if (e < E) {
        int d = edge_val(ei32, ei64, is64, (size_t)E + e);
        atomicAdd(&off[d + 1], 1);
    }
}

__global__ __launch_bounds__(256) void scan_block(int* a, int n, int* sums) {
    int b = blockIdx.x;
    int t = threadIdx.x;
    int base = b * 2048 + t * 8;
    int v[8];
    int s = 0;
#pragma unroll
    for (int i = 0; i < 8; ++i) {
        int x = (base + i < n) ? a[base + i] : 0;
        s += x;
        v[i] = s;
    }
    __shared__ int tot[256];
    tot[t] = s;
    __syncthreads();
    for (int o = 1; o < 256; o <<= 1) {
        int x = (t >= o) ? tot[t - o] : 0;
        __syncthreads();
        if (t >= o) tot[t] += x;
        __syncthreads();
    }
    int excl = (t == 0) ? 0 : tot[t - 1];
#pragma unroll
    for (int i = 0; i < 8; ++i)
        if (base + i < n) a[base + i] = v[i] + excl;
    if (t == 255 && sums) sums[b] = tot[255];
}

__global__ void scan_sums(int* sums, int nb) {
    if (threadIdx.x == 0 && blockIdx.x == 0) {
        int run = 0;
        for (int i = 0; i < nb; ++i) {
            int v = sums[i];
            sums[i] = run;
            run += v;
        }
    }
}

__global__ __launch_bounds__(256) void scan_add(int* a, int n, const int* sums) {
    int b = blockIdx.x;
    int add = sums[b];
    int base = b * 2048;
    for (int i = threadIdx.x; i < 2048; i += 256) {
        int idx = base + i;
        if (idx < n) a[idx] += add;
    }
}

__global__ void scatter_kernel(const int* ei32, const long long* ei64, const int* flag,
                               int E, const int* off, int* pos, int* csr) {
    int is64 = *flag;
    int e = blockIdx.x * blockDim.x + threadIdx.x;
    if (e < E) {
        int s = edge_val(ei32, ei64, is64, (size_t)e);
        int d = edge_val(ei32, ei64, is64, (size_t)E + e);
        int slot = atomicAdd(&pos[d], 1);
        csr[off[d] + slot] = s;
    }
}

// ---------------- fp32 -> bf16 conversion (x) ----------------
__global__ __launch_bounds__(256) void cvt_bf16(const float* __restrict__ in,
                                                unsigned short* __restrict__ outb,
                                                long long n8) {
    long long i = (long long)blockIdx.x * 256 + threadIdx.x;  // one per 8 elems
    if (i >= n8) return;
    const float4* p = (const float4*)(in + i * 8);
    float4 a = p[0], b = p[1];
    uint4 o;
    o.x = (unsigned)f2bf(a.x) | ((unsigned)f2bf(a.y) << 16);
    o.y = (unsigned)f2bf(a.z) | ((unsigned)f2bf(a.w) << 16);
    o.z = (unsigned)f2bf(b.x) | ((unsigned)f2bf(b.y) << 16);
    o.w = (unsigned)f2bf(b.z) | ((unsigned)f2bf(b.w) << 16);
    ((uint4*)(outb))[i] = o;
}

// ---------------- weight -> MFMA B-fragment layout ----------------
// frag fi covers (ct, ks); within frag, lane holds B[k0+j][n], j=0..7 contig,
// k0 = ks*32 + (lane>>4)*8, n = ct*16 + (lane&15).  16B per lane.
// W1: Wcat[256][128] = [W1_l (128x128); W1_r (128x128)], 64 frags.
__global__ __launch_bounds__(256) void mk_w1frag(const float* __restrict__ Wl,
                                                 const float* __restrict__ Wr,
                                                 uint4* __restrict__ frag) {
    int tid = blockIdx.x * 256 + threadIdx.x;   // 4096 total
    if (tid >= 4096) return;
    int fi = tid >> 6, lane = tid & 63;
    int ct = fi >> 3, ks = fi & 7;
    int k0 = ks * 32 + (lane >> 4) * 8;
    int n = ct * 16 + (lane & 15);
    unsigned short e[8];
#pragma unroll
    for (int j = 0; j < 8; ++j) {
        int k = k0 + j;
        float v = (k < 128) ? Wl[k * 128 + n] : Wr[(k - 128) * 128 + n];
        e[j] = f2bf(v);
    }
    uint4 o;
    o.x = (unsigned)e[0] | ((unsigned)e[1] << 16);
    o.y = (unsigned)e[2] | ((unsigned)e[3] << 16);
    o.z = (unsigned)e[4] | ((unsigned)e[5] << 16);
    o.w = (unsigned)e[6] | ((unsigned)e[7] << 16);
    frag[tid] = o;
}

// W2: Wcat2[128][128] = [W2_l | W2_r] (both 128x64), 32 frags (ct 0..7, ks 0..3).
__global__ __launch_bounds__(256) void mk_w2frag(const float* __restrict__ Wl,
                                                 const float* __restrict__ Wr,
                                                 uint4* __restrict__ frag) {
    int tid = blockIdx.x * 256 + threadIdx.x;   // 2048 total
    if (tid >= 2048) return;
    int fi = tid >> 6, lane = tid & 63;
    int ct = fi >> 2, ks = fi & 3;
    int k0 = ks * 32 + (lane >> 4) * 8;
    int n = ct * 16 + (lane & 15);
    unsigned short e[8];
#pragma unroll
    for (int j = 0; j < 8; ++j) {
        int k = k0 + j;
        float v = (n < 64) ? Wl[k * 64 + n] : Wr[k * 64 + (n - 64)];
        e[j] = f2bf(v);
    }
    uint4 o;
    o.x = (unsigned)e[0] | ((unsigned)e[1] << 16);
    o.y = (unsigned)e[2] | ((unsigned)e[3] << 16);
    o.z = (unsigned)e[4] | ((unsigned)e[5] << 16);
    o.w = (unsigned)e[6] | ((unsigned)e[7] << 16);
    frag[tid] = o;
}

// ---------------- mean aggregation, D=128 bf16 ----------------
// one wave per node; half = lane>>5 picks edge of pair, l32 = lane&31 picks
// 4-dim chunk (uint2 = 4 bf16). 8 edges / iter, 4 loads in flight.
__global__ __launch_bounds__(256) void agg_mean128_bf(const unsigned short* __restrict__ Xb,
                                                      const int* __restrict__ off,
                                                      const int* __restrict__ csr,
                                                      unsigned short* __restrict__ outb,
                                                      int n_nodes) {
    int node = blockIdx.x * 4 + (threadIdx.x >> 6);
    if (node >= n_nodes) return;
    int lane = threadIdx.x & 63;
    int half = lane >> 5;
    int l32 = lane & 31;
    int s0 = off[node], s1 = off[node + 1];
    float a0 = 0.f, a1 = 0.f, a2 = 0.f, a3 = 0.f;
    float b0 = 0.f, b1 = 0.f, b2 = 0.f, b3 = 0.f;
    float c0 = 0.f, c1 = 0.f, c2 = 0.f, c3 = 0.f;
    float d0 = 0.f, d1 = 0.f, d2 = 0.f, d3 = 0.f;
    int j = s0;
    for (; j + 8 <= s1; j += 8) {
        int p0 = csr[j + half];
        int p1 = csr[j + 2 + half];
        int p2 = csr[j + 4 + half];
        int p3 = csr[j + 6 + half];
        uint2 v0 = ((const uint2*)(Xb + (size_t)p0 * 128))[l32];
        uint2 v1 = ((const uint2*)(Xb + (size_t)p1 * 128))[l32];
        uint2 v2 = ((const uint2*)(Xb + (size_t)p2 * 128))[l32];
        uint2 v3 = ((const uint2*)(Xb + (size_t)p3 * 128))[l32];
        a0 += bflo(v0.x); a1 += bfhi(v0.x); a2 += bflo(v0.y); a3 += bfhi(v0.y);
        b0 += bflo(v1.x); b1 += bfhi(v1.x); b2 += bflo(v1.y); b3 += bfhi(v1.y);
        c0 += bflo(v2.x); c1 += bfhi(v2.x); c2 += bflo(v2.y); c3 += bfhi(v2.y);
        d0 += bflo(v3.x); d1 += bfhi(v3.x); d2 += bflo(v3.y); d3 += bfhi(v3.y);
    }
    for (; j + 2 <= s1; j += 2) {
        int p = csr[j + half];
        uint2 v = ((const uint2*)(Xb + (size_t)p * 128))[l32];
        a0 += bflo(v.x); a1 += bfhi(v.x); a2 += bflo(v.y); a3 += bfhi(v.y);
    }
    if (j < s1 && half == 0) {
        int p = csr[j];
        uint2 v = ((const uint2*)(Xb + (size_t)p * 128))[l32];
        a0 += bflo(v.x); a1 += bfhi(v.x); a2 += bflo(v.y); a3 += bfhi(v.y);
    }
    float s0f = a0 + b0 + c0 + d0;
    float s1f = a1 + b1 + c1 + d1;
    float s2f = a2 + b2 + c2 + d2;
    float s3f = a3 + b3 + c3 + d3;
    s0f += __shfl(s0f, lane ^ 32);
    s1f += __shfl(s1f, lane ^ 32);
    s2f += __shfl(s2f, lane ^ 32);
    s3f += __shfl(s3f, lane ^ 32);
    int deg = s1 - s0;
    float inv = (deg > 0) ? 1.0f / (float)deg : 0.0f;
    if (half == 0) {
        uint2 o;
        o.x = (unsigned)f2bf(s0f * inv) | ((unsigned)f2bf(s1f * inv) << 16);
        o.y = (unsigned)f2bf(s2f * inv) | ((unsigned)f2bf(s3f * inv) << 16);
        ((uint2*)(outb + (size_t)node * 128))[l32] = o;
    }
}

// ---------------- mean aggregation, D=64 bf16, epilogue +w2 -> fp32 out ------
__global__ __launch_bounds__(256) void agg_mean64_bf_ep(const unsigned short* __restrict__ Zb,
                                                        const float* __restrict__ Wadd,
                                                        const int* __restrict__ off,
                                                        const int* __restrict__ csr,
                                                        float* __restrict__ out,
                                                        int n_nodes) {
    int node = blockIdx.x * 4 + (threadIdx.x >> 6);
    if (node >= n_nodes) return;
    int lane = threadIdx.x & 63;
    int half = lane >> 5;
    int l32 = lane & 31;
    int s0 = off[node], s1 = off[node + 1];
    float a0 = 0.f, a1 = 0.f, b0 = 0.f, b1 = 0.f;
    float c0 = 0.f, c1 = 0.f, d0 = 0.f, d1 = 0.f;
    int j = s0;
    for (; j + 8 <= s1; j += 8) {
        int p0 = csr[j + half];
        int p1 = csr[j + 2 + half];
        int p2 = csr[j + 4 + half];
        int p3 = csr[j + 6 + half];
        unsigned v0 = ((const unsigned*)(Zb + (size_t)p0 * 64))[l32];
        unsigned v1 = ((const unsigned*)(Zb + (size_t)p1 * 64))[l32];
        unsigned v2 = ((const unsigned*)(Zb + (size_t)p2 * 64))[l32];
        unsigned v3 = ((const unsigned*)(Zb + (size_t)p3 * 64))[l32];
        a0 += bflo(v0); a1 += bfhi(v0);
        b0 += bflo(v1); b1 += bfhi(v1);
        c0 += bflo(v2); c1 += bfhi(v2);
        d0 += bflo(v3); d1 += bfhi(v3);
    }
    for (; j + 2 <= s1; j += 2) {
        int p = csr[j + half];
        unsigned v = ((const unsigned*)(Zb + (size_t)p * 64))[l32];
        a0 += bflo(v); a1 += bfhi(v);
    }
    if (j < s1 && half == 0) {
        int p = csr[j];
        unsigned v = ((const unsigned*)(Zb + (size_t)p * 64))[l32];
        a0 += bflo(v); a1 += bfhi(v);
    }
    float s0f = a0 + b0 + c0 + d0;
    float s1f = a1 + b1 + c1 + d1;
    s0f += __shfl(s0f, lane ^ 32);
    s1f += __shfl(s1f, lane ^ 32);
    int deg = s1 - s0;
    float inv = (deg > 0) ? 1.0f / (float)deg : 0.0f;
    if (half == 0) {
        float2 wv = ((const float2*)(Wadd + (size_t)node * 64))[l32];
        float2 r;
        r.x = s0f * inv + wv.x;
        r.y = s1f * inv + wv.y;
        ((float2*)(out + (size_t)node * 64))[l32] = r;
    }
}

// ---------------- GEMM1 (MFMA): hb = relu([mean|x] @ Wcat + b1), K=256 -------
// block = 4 waves, 128 rows; wave: 2 m-tiles x 8 col-tiles, K preloaded in regs.
__global__ __launch_bounds__(256, 2) void gemm1_mfma(const unsigned short* __restrict__ meanb,
                                                     const unsigned short* __restrict__ xb,
                                                     const uint4* __restrict__ wfrag,
                                                     const float* __restrict__ bias,
                                                     unsigned short* __restrict__ hb,
                                                     int nrows) {
    __shared__ uint4 sW[4096];   // 64 KB
    for (int i = threadIdx.x; i < 4096; i += 256) sW[i] = wfrag[i];
    __syncthreads();
    const int wid = threadIdx.x >> 6, lane = threadIdx.x & 63;
    const int quad = lane >> 4, l16 = lane & 15;
    const int m0 = blockIdx.x * 128 + wid * 32;

    bf16x8 af[2][8];
#pragma unroll
    for (int mt = 0; mt < 2; ++mt) {
        int row = m0 + mt * 16 + l16;
        row = (row < nrows) ? row : (nrows - 1);
        const uint4* mrow = (const uint4*)(meanb + (size_t)row * 128);
        const uint4* xrow = (const uint4*)(xb + (size_t)row * 128);
#pragma unroll
        for (int ks = 0; ks < 4; ++ks) {
            af[mt][ks]     = __builtin_bit_cast(bf16x8, mrow[ks * 4 + quad]);
            af[mt][ks + 4] = __builtin_bit_cast(bf16x8, xrow[ks * 4 + quad]);
        }
    }

    f32x4 acc[2][8];
#pragma unroll
    for (int mt = 0; mt < 2; ++mt)
#pragma unroll
        for (int ct = 0; ct < 8; ++ct) acc[mt][ct] = (f32x4){0.f, 0.f, 0.f, 0.f};

#pragma unroll
    for (int ct = 0; ct < 8; ++ct) {
#pragma unroll
        for (int ks = 0; ks < 8; ++ks) {
            bf16x8 bf = __builtin_bit_cast(bf16x8, sW[(ct * 8 + ks) * 64 + lane]);
            acc[0][ct] = __builtin_amdgcn_mfma_f32_16x16x32_bf16(af[0][ks], bf, acc[0][ct], 0, 0, 0);
            acc[1][ct] = __builtin_amdgcn_mfma_f32_16x16x32_bf16(af[1][ks], bf, acc[1][ct], 0, 0, 0);
        }
    }

#pragma unroll
    for (int mt = 0; mt < 2; ++mt) {
#pragma unroll
        for (int ct = 0; ct < 8; ++ct) {
            int col = ct * 16 + l16;
            float bb = bias[col];
#pragma unroll
            for (int r = 0; r < 4; ++r) {
                int row = m0 + mt * 16 + quad * 4 + r;
                if (row < nrows) {
                    float v = fmaxf(acc[mt][ct][r] + bb, 0.f);
                    hb[(size_t)row * 128 + col] = f2bf(v);
                }
            }
        }
    }
}

// ---------------- GEMM2 (MFMA): z2 = hb@W2_l (bf16), w2 = hb@W2_r + b2 (fp32)
// Wcat2 = [W2_l | W2_r] (128 x 128), K=128.
__global__ __launch_bounds__(256, 2) void gemm2_mfma(const unsigned short* __restrict__ hb,
                                                     const uint4* __restrict__ wfrag,
                                                     const float* __restrict__ bias,
                                                     unsigned short* __restrict__ z2,
                                                     float* __restrict__ w2,
                                                     int nrows) {
    __shared__ uint4 sW[2048];   // 32 KB
    for (int i = threadIdx.x; i < 2048; i += 256) sW[i] = wfrag[i];
    __syncthreads();
    const int wid = threadIdx.x >> 6, lane = threadIdx.x & 63;
    const int quad = lane >> 4, l16 = lane & 15;
    const int m0 = blockIdx.x * 128 + wid * 32;

    bf16x8 af[2][4];
#pragma unroll
    for (int mt = 0; mt < 2; ++mt) {
        int row = m0 + mt * 16 + l16;
        row = (row < nrows) ? row : (nrows - 1);
        const uint4* hrow = (const uint4*)(hb + (size_t)row * 128);
#pragma unroll
        for (int ks = 0; ks < 4; ++ks)
            af[mt][ks] = __builtin_bit_cast(bf16x8, hrow[ks * 4 + quad]);
    }

    f32x4 acc[2][8];
#pragma unroll
    for (int mt = 0; mt < 2; ++mt)
#pragma unroll
        for (int ct = 0; ct < 8; ++ct) acc[mt][ct] = (f32x4){0.f, 0.f, 0.f, 0.f};

#pragma unroll
    for (int ct = 0; ct < 8; ++ct) {
#pragma unroll
        for (int ks = 0; ks < 4; ++ks) {
            bf16x8 bf = __builtin_bit_cast(bf16x8, sW[(ct * 4 + ks) * 64 + lane]);
            acc[0][ct] = __builtin_amdgcn_mfma_f32_16x16x32_bf16(af[0][ks], bf, acc[0][ct], 0, 0, 0);
            acc[1][ct] = __builtin_amdgcn_mfma_f32_16x16x32_bf16(af[1][ks], bf, acc[1][ct], 0, 0, 0);
        }
    }

#pragma unroll
    for (int mt = 0; mt < 2; ++mt) {
#pragma unroll
        for (int ct = 0; ct < 8; ++ct) {
            int col = ct * 16 + l16;
#pragma unroll
            for (int r = 0; r < 4; ++r) {
                int row = m0 + mt * 16 + quad * 4 + r;
                if (row < nrows) {
                    if (col < 64) {
                        z2[(size_t)row * 64 + col] = f2bf(acc[mt][ct][r]);
                    } else {
                        w2[(size_t)row * 64 + (col - 64)] = acc[mt][ct][r] + bias[col - 64];
                    }
                }
            }
        }
    }
}

extern "C" void kernel_launch(void* const* d_in, const int* in_sizes, int n_in,
                              void* d_out, int out_size, void* d_ws, size_t ws_size,
                              hipStream_t stream) {
    const float* x    = (const float*)d_in[0];
    const float* W1_l = (const float*)d_in[1];
    const float* b1   = (const float*)d_in[2];
    const float* W1_r = (const float*)d_in[3];
    const float* W2_l = (const float*)d_in[4];
    const float* b2   = (const float*)d_in[5];
    const float* W2_r = (const float*)d_in[6];
    const void*  ei   = d_in[7];
    float* out = (float*)d_out;

    const int N = in_sizes[0] / 128;      // 100000
    const int E = in_sizes[7] / 2;        // 1600000

    // workspace layout
    uintptr_t base = (uintptr_t)d_ws;
    int* flag = (int*)base;               // 1 int
    int* sums = (int*)(base + 64);        // up to 112 ints
    int* off  = (int*)(base + 512);       // N+1
    int* pos  = off + (N + 1);            // N
    int* csr  = pos + N;                  // E
    uintptr_t p = ((uintptr_t)(csr + E) + 255) & ~(uintptr_t)255;
    unsigned short* xb    = (unsigned short*)p; p += (size_t)N * 128 * 2;   // bf16 x
    unsigned short* meanb = (unsigned short*)p; p += (size_t)N * 128 * 2;   // bf16 mean / z2
    unsigned short* hb    = (unsigned short*)p; p += (size_t)N * 128 * 2;   // bf16 h
    uint4* w1frag = (uint4*)p; p += 4096 * 16;
    uint4* w2frag = (uint4*)p; p += 2048 * 16;
    unsigned short* z2 = meanb;            // meanb dead after gemm1
    float* w2 = (float*)xb;                // xb dead after gemm1

    const int* ei32 = (const int*)ei;
    const long long* ei64 = (const long long*)ei;

    hipMemsetAsync(off, 0, sizeof(int) * (size_t)(2 * N + 1), stream);

    detect_i64<<<1, 1, 0, stream>>>(ei, N, flag);

    // conversions (independent of CSR)
    long long n8 = (long long)N * 128 / 8;
    cvt_bf16<<<(int)((n8 + 255) / 256), 256, 0, stream>>>(x, xb, n8);
    mk_w1frag<<<16, 256, 0, stream>>>(W1_l, W1_r, w1frag);
    mk_w2frag<<<8, 256, 0, stream>>>(W2_l, W2_r, w2frag);

    int eblocks = (E + 255) / 256;
    hist_kernel<<<eblocks, 256, 0, stream>>>(ei32, ei64, flag, E, off);

    int NB = (N + 2047) / 2048;
    scan_block<<<NB, 256, 0, stream>>>(off + 1, N, sums);
    scan_sums<<<1, 64, 0, stream>>>(sums, NB);
    scan_add<<<NB, 256, 0, stream>>>(off + 1, N, sums);

    scatter_kernel<<<eblocks, 256, 0, stream>>>(ei32, ei64, flag, E, off, pos, csr);

    int ablocks = (N + 3) / 4;
    int gblocks = (N + 127) / 128;

    // layer 1
    agg_mean128_bf<<<ablocks, 256, 0, stream>>>(xb, off, csr, meanb, N);
    gemm1_mfma<<<gblocks, 256, 0, stream>>>(meanb, xb, w1frag, b1, hb, N);

    // layer 2 (commuted)
    gemm2_mfma<<<gblocks, 256, 0, stream>>>(hb, w2frag, b2, z2, w2, N);
    agg_mean64_bf_ep<<<ablocks, 256, 0, stream>>>(z2, w2, off, csr, out, N);
}

// Round 4
// 347.619 us; speedup vs baseline: 2.2919x; 1.3320x over previous
//
#include <hip/hip_runtime.h>
#include <hip/hip_bf16.h>
#include <cstdint>

// GraphSAGE 2-layer, bf16 features + fp32 accumulate, MFMA GEMMs.
// Layer1: h   = relu([mean_agg(x) | x] @ [W1_l; W1_r] + b1)   (K=256 MFMA GEMM)
// Layer2: out = mean_agg(h @ W2_l) + h @ W2_r + b2            (agg commutes w/ linear)
// CSR built via dst-bucketed partition (256 nodes/bucket); all per-edge atomics
// in LDS; csr writes per bucket land in a contiguous 16KB region (full lines).

typedef __bf16 bf16x8 __attribute__((ext_vector_type(8)));
typedef float f32x4 __attribute__((ext_vector_type(4)));

#define MAXBUCK 400   // >= ceil(100352/256); N=100000 -> 391 buckets
#define MAXEPT 16

__device__ __forceinline__ unsigned short f2bf(float f) {
    union { float f; unsigned int u; } v; v.f = f;
    unsigned int u = v.u;
    unsigned int r = ((u >> 16) & 1u) + 0x7fffu;
    return (unsigned short)((u + r) >> 16);
}
__device__ __forceinline__ float bflo(unsigned int u) {
    union { unsigned int u; float f; } v; v.u = u << 16; return v.f;
}
__device__ __forceinline__ float bfhi(unsigned int u) {
    union { unsigned int u; float f; } v; v.u = u & 0xffff0000u; return v.f;
}

// ---------------- edge dtype detection ----------------
__global__ void detect_i64(const void* ei, int n_nodes, int* flag) {
    const long long* p = (const long long*)ei;
    int ok = 1;
    for (int i = 0; i < 8; ++i) {
        long long v = p[i];
        if (v < 0 || v >= n_nodes) ok = 0;
    }
    *flag = ok;
}

__device__ __forceinline__ int edge_val(const int* ei32, const long long* ei64,
                                        int is64, size_t idx) {
    return is64 ? (int)ei64[idx] : ei32[idx];
}

// ---------------- CSR build: bucketed partition ----------------
// pass1: coarse hist of dst>>8 into nbuck counters
__global__ __launch_bounds__(256) void pass1_hist(const int* ei32, const long long* ei64,
                                                  const int* flag, int E, int nbuck,
                                                  int* bucket_cnt) {
    __shared__ int lhist[MAXBUCK];
    for (int i = threadIdx.x; i < nbuck; i += 256) lhist[i] = 0;
    __syncthreads();
    int is64 = *flag;
    int stride = gridDim.x * 256;
    for (int e = blockIdx.x * 256 + threadIdx.x; e < E; e += stride) {
        int d = edge_val(ei32, ei64, is64, (size_t)E + e);
        atomicAdd(&lhist[d >> 8], 1);
    }
    __syncthreads();
    for (int i = threadIdx.x; i < nbuck; i += 256) {
        int c = lhist[i];
        if (c) atomicAdd(&bucket_cnt[i], c);
    }
}

// scan nbuck counts -> bucket_base[nbuck+1], init bucket_pos = bucket_base
__global__ __launch_bounds__(256) void bucket_scan(const int* bucket_cnt, int nbuck,
                                                   int* bucket_base, int* bucket_pos) {
    int t = threadIdx.x;
    int i0 = 2 * t, i1 = 2 * t + 1;
    int a0 = (i0 < nbuck) ? bucket_cnt[i0] : 0;
    int a1 = (i1 < nbuck) ? bucket_cnt[i1] : 0;
    int tsum = a0 + a1;
    __shared__ int sc[256];
    sc[t] = tsum;
    __syncthreads();
    for (int o = 1; o < 256; o <<= 1) {
        int x = (t >= o) ? sc[t - o] : 0;
        __syncthreads();
        if (t >= o) sc[t] += x;
        __syncthreads();
    }
    int excl = sc[t] - tsum;
    if (i0 <= nbuck) { bucket_base[i0] = excl; if (i0 < nbuck) bucket_pos[i0] = excl; }
    if (i1 <= nbuck) { bucket_base[i1] = excl + a0; if (i1 < nbuck) bucket_pos[i1] = excl + a0; }
    if (t == 255 && 511 > nbuck) {}  // nothing
    if (t == 255) bucket_base[nbuck] = sc[255];
}

// pass2: partition edges into bucket-ordered (src,dst) pairs
__global__ __launch_bounds__(256) void pass2_partition(const int* ei32, const long long* ei64,
                                                       const int* flag, int E, int ept,
                                                       int nbuck, int* bucket_pos,
                                                       uint2* ebuf) {
    __shared__ int lhist[MAXBUCK];
    __shared__ int gbase[MAXBUCK];
    for (int i = threadIdx.x; i < nbuck; i += 256) lhist[i] = 0;
    __syncthreads();
    int is64 = *flag;
    int base_e = blockIdx.x * (ept * 256);
    uint2 ed[MAXEPT];
    int slot[MAXEPT];
#pragma unroll 4
    for (int i = 0; i < ept; ++i) {
        int e = base_e + i * 256 + threadIdx.x;
        if (e < E) {
            int s = edge_val(ei32, ei64, is64, (size_t)e);
            int d = edge_val(ei32, ei64, is64, (size_t)E + e);
            ed[i] = make_uint2((unsigned)s, (unsigned)d);
            slot[i] = atomicAdd(&lhist[d >> 8], 1);
        } else {
            slot[i] = -1;
        }
    }
    __syncthreads();
    for (int i = threadIdx.x; i < nbuck; i += 256) {
        int c = lhist[i];
        gbase[i] = c ? atomicAdd(&bucket_pos[i], c) : 0;
    }
    __syncthreads();
#pragma unroll 4
    for (int i = 0; i < ept; ++i) {
        if (slot[i] >= 0) {
            int b = ed[i].y >> 8;
            ebuf[gbase[b] + slot[i]] = ed[i];
        }
    }
}

// pass3: one block per bucket -> per-node counts, scan, off[] and csr[]
__global__ __launch_bounds__(256) void pass3_finalize(const uint2* __restrict__ ebuf,
                                                      const int* __restrict__ bucket_base,
                                                      int nbuck, int N, int E,
                                                      int* __restrict__ off,
                                                      int* __restrict__ csr) {
    __shared__ int lcnt[256];
    __shared__ int lexcl[256];
    __shared__ int sc[256];
    int b = blockIdx.x;
    int t = threadIdx.x;
    int d0 = b << 8;
    int nb = N - d0; if (nb > 256) nb = 256;
    int base = bucket_base[b];
    int m = bucket_base[b + 1] - base;

    lcnt[t] = 0;
    __syncthreads();
    for (int j = t; j < m; j += 256) {
        int d = (int)ebuf[base + j].y;
        atomicAdd(&lcnt[d - d0], 1);
    }
    __syncthreads();
    int v = lcnt[t];
    sc[t] = v;
    __syncthreads();
    for (int o = 1; o < 256; o <<= 1) {
        int x = (t >= o) ? sc[t - o] : 0;
        __syncthreads();
        if (t >= o) sc[t] += x;
        __syncthreads();
    }
    int excl = sc[t] - v;
    lexcl[t] = excl;
    if (t < nb) off[d0 + t] = base + excl;
    if (b == nbuck - 1 && t == 0) off[N] = E;
    lcnt[t] = 0;   // reuse as running pos
    __syncthreads();
    for (int j = t; j < m; j += 256) {
        uint2 ed = ebuf[base + j];
        int li = (int)ed.y - d0;
        int slot = atomicAdd(&lcnt[li], 1);
        csr[base + lexcl[li] + slot] = (int)ed.x;
    }
}

// ---------------- fp32 -> bf16 conversion (x) ----------------
__global__ __launch_bounds__(256) void cvt_bf16(const float* __restrict__ in,
                                                unsigned short* __restrict__ outb,
                                                long long n8) {
    long long i = (long long)blockIdx.x * 256 + threadIdx.x;  // one per 8 elems
    if (i >= n8) return;
    const float4* p = (const float4*)(in + i * 8);
    float4 a = p[0], b = p[1];
    uint4 o;
    o.x = (unsigned)f2bf(a.x) | ((unsigned)f2bf(a.y) << 16);
    o.y = (unsigned)f2bf(a.z) | ((unsigned)f2bf(a.w) << 16);
    o.z = (unsigned)f2bf(b.x) | ((unsigned)f2bf(b.y) << 16);
    o.w = (unsigned)f2bf(b.z) | ((unsigned)f2bf(b.w) << 16);
    ((uint4*)(outb))[i] = o;
}

// ---------------- weight -> MFMA B-fragment layout ----------------
// frag fi covers (ct, ks); lane holds B[k0+j][n], j=0..7, k0=ks*32+(lane>>4)*8,
// n = ct*16 + (lane&15). W1: Wcat[256][128] = [W1_l; W1_r], 64 frags.
__global__ __launch_bounds__(256) void mk_w1frag(const float* __restrict__ Wl,
                                                 const float* __restrict__ Wr,
                                                 uint4* __restrict__ frag) {
    int tid = blockIdx.x * 256 + threadIdx.x;   // 4096 total
    if (tid >= 4096) return;
    int fi = tid >> 6, lane = tid & 63;
    int ct = fi >> 3, ks = fi & 7;
    int k0 = ks * 32 + (lane >> 4) * 8;
    int n = ct * 16 + (lane & 15);
    unsigned short e[8];
#pragma unroll
    for (int j = 0; j < 8; ++j) {
        int k = k0 + j;
        float v = (k < 128) ? Wl[k * 128 + n] : Wr[(k - 128) * 128 + n];
        e[j] = f2bf(v);
    }
    uint4 o;
    o.x = (unsigned)e[0] | ((unsigned)e[1] << 16);
    o.y = (unsigned)e[2] | ((unsigned)e[3] << 16);
    o.z = (unsigned)e[4] | ((unsigned)e[5] << 16);
    o.w = (unsigned)e[6] | ((unsigned)e[7] << 16);
    frag[tid] = o;
}

// W2: Wcat2[128][128] = [W2_l | W2_r] (both 128x64), 32 frags.
__global__ __launch_bounds__(256) void mk_w2frag(const float* __restrict__ Wl,
                                                 const float* __restrict__ Wr,
                                                 uint4* __restrict__ frag) {
    int tid = blockIdx.x * 256 + threadIdx.x;   // 2048 total
    if (tid >= 2048) return;
    int fi = tid >> 6, lane = tid & 63;
    int ct = fi >> 2, ks = fi & 3;
    int k0 = ks * 32 + (lane >> 4) * 8;
    int n = ct * 16 + (lane & 15);
    unsigned short e[8];
#pragma unroll
    for (int j = 0; j < 8; ++j) {
        int k = k0 + j;
        float v = (n < 64) ? Wl[k * 64 + n] : Wr[k * 64 + (n - 64)];
        e[j] = f2bf(v);
    }
    uint4 o;
    o.x = (unsigned)e[0] | ((unsigned)e[1] << 16);
    o.y = (unsigned)e[2] | ((unsigned)e[3] << 16);
    o.z = (unsigned)e[4] | ((unsigned)e[5] << 16);
    o.w = (unsigned)e[6] | ((unsigned)e[7] << 16);
    frag[tid] = o;
}

// ---------------- mean aggregation, D=128 bf16 ----------------
__global__ __launch_bounds__(256) void agg_mean128_bf(const unsigned short* __restrict__ Xb,
                                                      const int* __restrict__ off,
                                                      const int* __restrict__ csr,
                                                      unsigned short* __restrict__ outb,
                                                      int n_nodes) {
    int node = blockIdx.x * 4 + (threadIdx.x >> 6);
    if (node >= n_nodes) return;
    int lane = threadIdx.x & 63;
    int half = lane >> 5;
    int l32 = lane & 31;
    int s0 = off[node], s1 = off[node + 1];
    float a0 = 0.f, a1 = 0.f, a2 = 0.f, a3 = 0.f;
    float b0 = 0.f, b1 = 0.f, b2 = 0.f, b3 = 0.f;
    float c0 = 0.f, c1 = 0.f, c2 = 0.f, c3 = 0.f;
    float d0 = 0.f, d1 = 0.f, d2 = 0.f, d3 = 0.f;
    int j = s0;
    for (; j + 8 <= s1; j += 8) {
        int p0 = csr[j + half];
        int p1 = csr[j + 2 + half];
        int p2 = csr[j + 4 + half];
        int p3 = csr[j + 6 + half];
        uint2 v0 = ((const uint2*)(Xb + (size_t)p0 * 128))[l32];
        uint2 v1 = ((const uint2*)(Xb + (size_t)p1 * 128))[l32];
        uint2 v2 = ((const uint2*)(Xb + (size_t)p2 * 128))[l32];
        uint2 v3 = ((const uint2*)(Xb + (size_t)p3 * 128))[l32];
        a0 += bflo(v0.x); a1 += bfhi(v0.x); a2 += bflo(v0.y); a3 += bfhi(v0.y);
        b0 += bflo(v1.x); b1 += bfhi(v1.x); b2 += bflo(v1.y); b3 += bfhi(v1.y);
        c0 += bflo(v2.x); c1 += bfhi(v2.x); c2 += bflo(v2.y); c3 += bfhi(v2.y);
        d0 += bflo(v3.x); d1 += bfhi(v3.x); d2 += bflo(v3.y); d3 += bfhi(v3.y);
    }
    for (; j + 2 <= s1; j += 2) {
        int p = csr[j + half];
        uint2 v = ((const uint2*)(Xb + (size_t)p * 128))[l32];
        a0 += bflo(v.x); a1 += bfhi(v.x); a2 += bflo(v.y); a3 += bfhi(v.y);
    }
    if (j < s1 && half == 0) {
        int p = csr[j];
        uint2 v = ((const uint2*)(Xb + (size_t)p * 128))[l32];
        a0 += bflo(v.x); a1 += bfhi(v.x); a2 += bflo(v.y); a3 += bfhi(v.y);
    }
    float s0f = a0 + b0 + c0 + d0;
    float s1f = a1 + b1 + c1 + d1;
    float s2f = a2 + b2 + c2 + d2;
    float s3f = a3 + b3 + c3 + d3;
    s0f += __shfl(s0f, lane ^ 32);
    s1f += __shfl(s1f, lane ^ 32);
    s2f += __shfl(s2f, lane ^ 32);
    s3f += __shfl(s3f, lane ^ 32);
    int deg = s1 - s0;
    float inv = (deg > 0) ? 1.0f / (float)deg : 0.0f;
    if (half == 0) {
        uint2 o;
        o.x = (unsigned)f2bf(s0f * inv) | ((unsigned)f2bf(s1f * inv) << 16);
        o.y = (unsigned)f2bf(s2f * inv) | ((unsigned)f2bf(s3f * inv) << 16);
        ((uint2*)(outb + (size_t)node * 128))[l32] = o;
    }
}

// ---------------- mean aggregation, D=64 bf16, epilogue +w2 -> fp32 out ------
__global__ __launch_bounds__(256) void agg_mean64_bf_ep(const unsigned short* __restrict__ Zb,
                                                        const float* __restrict__ Wadd,
                                                        const int* __restrict__ off,
                                                        const int* __restrict__ csr,
                                                        float* __restrict__ out,
                                                        int n_nodes) {
    int node = blockIdx.x * 4 + (threadIdx.x >> 6);
    if (node >= n_nodes) return;
    int lane = threadIdx.x & 63;
    int half = lane >> 5;
    int l32 = lane & 31;
    int s0 = off[node], s1 = off[node + 1];
    float a0 = 0.f, a1 = 0.f, b0 = 0.f, b1 = 0.f;
    float c0 = 0.f, c1 = 0.f, d0 = 0.f, d1 = 0.f;
    int j = s0;
    for (; j + 8 <= s1; j += 8) {
        int p0 = csr[j + half];
        int p1 = csr[j + 2 + half];
        int p2 = csr[j + 4 + half];
        int p3 = csr[j + 6 + half];
        unsigned v0 = ((const unsigned*)(Zb + (size_t)p0 * 64))[l32];
        unsigned v1 = ((const unsigned*)(Zb + (size_t)p1 * 64))[l32];
        unsigned v2 = ((const unsigned*)(Zb + (size_t)p2 * 64))[l32];
        unsigned v3 = ((const unsigned*)(Zb + (size_t)p3 * 64))[l32];
        a0 += bflo(v0); a1 += bfhi(v0);
        b0 += bflo(v1); b1 += bfhi(v1);
        c0 += bflo(v2); c1 += bfhi(v2);
        d0 += bflo(v3); d1 += bfhi(v3);
    }
    for (; j + 2 <= s1; j += 2) {
        int p = csr[j + half];
        unsigned v = ((const unsigned*)(Zb + (size_t)p * 64))[l32];
        a0 += bflo(v); a1 += bfhi(v);
    }
    if (j < s1 && half == 0) {
        int p = csr[j];
        unsigned v = ((const unsigned*)(Zb + (size_t)p * 64))[l32];
        a0 += bflo(v); a1 += bfhi(v);
    }
    float s0f = a0 + b0 + c0 + d0;
    float s1f = a1 + b1 + c1 + d1;
    s0f += __shfl(s0f, lane ^ 32);
    s1f += __shfl(s1f, lane ^ 32);
    int deg = s1 - s0;
    float inv = (deg > 0) ? 1.0f / (float)deg : 0.0f;
    if (half == 0) {
        float2 wv = ((const float2*)(Wadd + (size_t)node * 64))[l32];
        float2 r;
        r.x = s0f * inv + wv.x;
        r.y = s1f * inv + wv.y;
        ((float2*)(out + (size_t)node * 64))[l32] = r;
    }
}

// ---------------- GEMM1 (MFMA): hb = relu([mean|x] @ Wcat + b1), K=256 -------
__global__ __launch_bounds__(256, 2) void gemm1_mfma(const unsigned short* __restrict__ meanb,
                                                     const unsigned short* __restrict__ xb,
                                                     const uint4* __restrict__ wfrag,
                                                     const float* __restrict__ bias,
                                                     unsigned short* __restrict__ hb,
                                                     int nrows) {
    __shared__ uint4 sW[4096];   // 64 KB
    for (int i = threadIdx.x; i < 4096; i += 256) sW[i] = wfrag[i];
    __syncthreads();
    const int wid = threadIdx.x >> 6, lane = threadIdx.x & 63;
    const int quad = lane >> 4, l16 = lane & 15;
    const int m0 = blockIdx.x * 128 + wid * 32;

    bf16x8 af[2][8];
#pragma unroll
    for (int mt = 0; mt < 2; ++mt) {
        int row = m0 + mt * 16 + l16;
        row = (row < nrows) ? row : (nrows - 1);
        const uint4* mrow = (const uint4*)(meanb + (size_t)row * 128);
        const uint4* xrow = (const uint4*)(xb + (size_t)row * 128);
#pragma unroll
        for (int ks = 0; ks < 4; ++ks) {
            af[mt][ks]     = __builtin_bit_cast(bf16x8, mrow[ks * 4 + quad]);
            af[mt][ks + 4] = __builtin_bit_cast(bf16x8, xrow[ks * 4 + quad]);
        }
    }

    f32x4 acc[2][8];
#pragma unroll
    for (int mt = 0; mt < 2; ++mt)
#pragma unroll
        for (int ct = 0; ct < 8; ++ct) acc[mt][ct] = (f32x4){0.f, 0.f, 0.f, 0.f};

#pragma unroll
    for (int ct = 0; ct < 8; ++ct) {
#pragma unroll
        for (int ks = 0; ks < 8; ++ks) {
            bf16x8 bf = __builtin_bit_cast(bf16x8, sW[(ct * 8 + ks) * 64 + lane]);
            acc[0][ct] = __builtin_amdgcn_mfma_f32_16x16x32_bf16(af[0][ks], bf, acc[0][ct], 0, 0, 0);
            acc[1][ct] = __builtin_amdgcn_mfma_f32_16x16x32_bf16(af[1][ks], bf, acc[1][ct], 0, 0, 0);
        }
    }

#pragma unroll
    for (int mt = 0; mt < 2; ++mt) {
#pragma unroll
        for (int ct = 0; ct < 8; ++ct) {
            int col = ct * 16 + l16;
            float bb = bias[col];
#pragma unroll
            for (int r = 0; r < 4; ++r) {
                int row = m0 + mt * 16 + quad * 4 + r;
                if (row < nrows) {
                    float v = fmaxf(acc[mt][ct][r] + bb, 0.f);
                    hb[(size_t)row * 128 + col] = f2bf(v);
                }
            }
        }
    }
}

// ---------------- GEMM2 (MFMA): z2 = hb@W2_l (bf16), w2 = hb@W2_r + b2 (fp32)
__global__ __launch_bounds__(256, 2) void gemm2_mfma(const unsigned short* __restrict__ hb,
                                                     const uint4* __restrict__ wfrag,
                                                     const float* __restrict__ bias,
                                                     unsigned short* __restrict__ z2,
                                                     float* __restrict__ w2,
                                                     int nrows) {
    __shared__ uint4 sW[2048];   // 32 KB
    for (int i = threadIdx.x; i < 2048; i += 256) sW[i] = wfrag[i];
    __syncthreads();
    const int wid = threadIdx.x >> 6, lane = threadIdx.x & 63;
    const int quad = lane >> 4, l16 = lane & 15;
    const int m0 = blockIdx.x * 128 + wid * 32;

    bf16x8 af[2][4];
#pragma unroll
    for (int mt = 0; mt < 2; ++mt) {
        int row = m0 + mt * 16 + l16;
        row = (row < nrows) ? row : (nrows - 1);
        const uint4* hrow = (const uint4*)(hb + (size_t)row * 128);
#pragma unroll
        for (int ks = 0; ks < 4; ++ks)
            af[mt][ks] = __builtin_bit_cast(bf16x8, hrow[ks * 4 + quad]);
    }

    f32x4 acc[2][8];
#pragma unroll
    for (int mt = 0; mt < 2; ++mt)
#pragma unroll
        for (int ct = 0; ct < 8; ++ct) acc[mt][ct] = (f32x4){0.f, 0.f, 0.f, 0.f};

#pragma unroll
    for (int ct = 0; ct < 8; ++ct) {
#pragma unroll
        for (int ks = 0; ks < 4; ++ks) {
            bf16x8 bf = __builtin_bit_cast(bf16x8, sW[(ct * 4 + ks) * 64 + lane]);
            acc[0][ct] = __builtin_amdgcn_mfma_f32_16x16x32_bf16(af[0][ks], bf, acc[0][ct], 0, 0, 0);
            acc[1][ct] = __builtin_amdgcn_mfma_f32_16x16x32_bf16(af[1][ks], bf, acc[1][ct], 0, 0, 0);
        }
    }

#pragma unroll
    for (int mt = 0; mt < 2; ++mt) {
#pragma unroll
        for (int ct = 0; ct < 8; ++ct) {
            int col = ct * 16 + l16;
#pragma unroll
            for (int r = 0; r < 4; ++r) {
                int row = m0 + mt * 16 + quad * 4 + r;
                if (row < nrows) {
                    if (col < 64) {
                        z2[(size_t)row * 64 + col] = f2bf(acc[mt][ct][r]);
                    } else {
                        w2[(size_t)row * 64 + (col - 64)] = acc[mt][ct][r] + bias[col - 64];
                    }
                }
            }
        }
    }
}

extern "C" void kernel_launch(void* const* d_in, const int* in_sizes, int n_in,
                              void* d_out, int out_size, void* d_ws, size_t ws_size,
                              hipStream_t stream) {
    const float* x    = (const float*)d_in[0];
    const float* W1_l = (const float*)d_in[1];
    const float* b1   = (const float*)d_in[2];
    const float* W1_r = (const float*)d_in[3];
    const float* W2_l = (const float*)d_in[4];
    const float* b2   = (const float*)d_in[5];
    const float* W2_r = (const float*)d_in[6];
    const void*  ei   = d_in[7];
    float* out = (float*)d_out;

    const int N = in_sizes[0] / 128;      // 100000
    const int E = in_sizes[7] / 2;        // 1600000
    const int nbuck = (N + 255) >> 8;     // 391

    // workspace layout
    uintptr_t base = (uintptr_t)d_ws;
    int* flag = (int*)base;                                   // 1 int
    int* bucket_cnt  = (int*)(base + 64);                     // nbuck
    int* bucket_base = bucket_cnt + MAXBUCK;                  // nbuck+1
    int* bucket_pos  = bucket_base + MAXBUCK + 1;             // nbuck
    int* off = (int*)(base + 4096 + 3 * MAXBUCK * 4);
    off = (int*)(((uintptr_t)off + 255) & ~(uintptr_t)255);   // N+1
    int* csr = off + (N + 1);                                 // E
    uintptr_t p = ((uintptr_t)(csr + E) + 255) & ~(uintptr_t)255;
    unsigned short* xb    = (unsigned short*)p; p += (size_t)N * 128 * 2;   // bf16 x
    unsigned short* meanb = (unsigned short*)p; p += (size_t)N * 128 * 2;   // bf16 mean / z2 / ebuf
    unsigned short* hb    = (unsigned short*)p; p += (size_t)N * 128 * 2;   // bf16 h
    uint4* w1frag = (uint4*)p; p += 4096 * 16;
    uint4* w2frag = (uint4*)p; p += 2048 * 16;
    uint2* ebuf = (uint2*)meanb;           // dead before agg_mean128_bf writes meanb
    unsigned short* z2 = meanb;            // meanb dead after gemm1
    float* w2 = (float*)xb;                // xb dead after gemm1

    const int* ei32 = (const int*)ei;
    const long long* ei64 = (const long long*)ei;

    hipMemsetAsync(bucket_cnt, 0, sizeof(int) * MAXBUCK, stream);

    detect_i64<<<1, 1, 0, stream>>>(ei, N, flag);

    // conversions (independent of CSR)
    long long n8 = (long long)N * 128 / 8;
    cvt_bf16<<<(int)((n8 + 255) / 256), 256, 0, stream>>>(x, xb, n8);
    mk_w1frag<<<16, 256, 0, stream>>>(W1_l, W1_r, w1frag);
    mk_w2frag<<<8, 256, 0, stream>>>(W2_l, W2_r, w2frag);

    // CSR build
    pass1_hist<<<512, 256, 0, stream>>>(ei32, ei64, flag, E, nbuck, bucket_cnt);
    bucket_scan<<<1, 256, 0, stream>>>(bucket_cnt, nbuck, bucket_base, bucket_pos);
    int ept = (E + 512 * 256 - 1) / (512 * 256);   // 13 for E=1.6M (<= MAXEPT)
    pass2_partition<<<512, 256, 0, stream>>>(ei32, ei64, flag, E, ept, nbuck,
                                             bucket_pos, ebuf);
    pass3_finalize<<<nbuck, 256, 0, stream>>>(ebuf, bucket_base, nbuck, N, E, off, csr);

    int ablocks = (N + 3) / 4;
    int gblocks = (N + 127) / 128;

    // layer 1
    agg_mean128_bf<<<ablocks, 256, 0, stream>>>(xb, off, csr, meanb, N);
    gemm1_mfma<<<gblocks, 256, 0, stream>>>(meanb, xb, w1frag, b1, hb, N);

    // layer 2 (commuted)
    gemm2_mfma<<<gblocks, 256, 0, stream>>>(hb, w2frag, b2, z2, w2, N);
    agg_mean64_bf_ep<<<ablocks, 256, 0, stream>>>(z2, w2, off, csr, out, N);
}

// Round 5
// 336.286 us; speedup vs baseline: 2.3691x; 1.0337x over previous
//
#include <hip/hip_runtime.h>
#include <hip/hip_bf16.h>
#include <cstdint>

// GraphSAGE 2-layer, bf16 features + fp32 accumulate, MFMA GEMMs.
// Layer1: h   = relu([mean_agg(x) | x] @ [W1_l; W1_r] + b1)   (K=256 MFMA GEMM)
// Layer2: out = mean_agg(h @ W2_l) + h @ W2_r + b2            (agg commutes w/ linear)
// CSR via dst-bucketed partition (LDS atomics only, contiguous csr writes).
// Aggs: 16B/lane gathers -- agg128: 4 edges/load, agg64: 8 edges/load.

typedef __bf16 bf16x8 __attribute__((ext_vector_type(8)));
typedef float f32x4 __attribute__((ext_vector_type(4)));

#define MAXBUCK 400   // >= ceil(100352/256); N=100000 -> 391 buckets
#define MAXEPT 16

__device__ __forceinline__ unsigned short f2bf(float f) {
    union { float f; unsigned int u; } v; v.f = f;
    unsigned int u = v.u;
    unsigned int r = ((u >> 16) & 1u) + 0x7fffu;
    return (unsigned short)((u + r) >> 16);
}
__device__ __forceinline__ float bflo(unsigned int u) {
    union { unsigned int u; float f; } v; v.u = u << 16; return v.f;
}
__device__ __forceinline__ float bfhi(unsigned int u) {
    union { unsigned int u; float f; } v; v.u = u & 0xffff0000u; return v.f;
}
__device__ __forceinline__ void unpack8_add(const uint4& v, float* a) {
    a[0] += bflo(v.x); a[1] += bfhi(v.x);
    a[2] += bflo(v.y); a[3] += bfhi(v.y);
    a[4] += bflo(v.z); a[5] += bfhi(v.z);
    a[6] += bflo(v.w); a[7] += bfhi(v.w);
}
__device__ __forceinline__ void unpack8_fma(const uint4& v, float w, float* a) {
    a[0] = fmaf(bflo(v.x), w, a[0]); a[1] = fmaf(bfhi(v.x), w, a[1]);
    a[2] = fmaf(bflo(v.y), w, a[2]); a[3] = fmaf(bfhi(v.y), w, a[3]);
    a[4] = fmaf(bflo(v.z), w, a[4]); a[5] = fmaf(bfhi(v.z), w, a[5]);
    a[6] = fmaf(bflo(v.w), w, a[6]); a[7] = fmaf(bfhi(v.w), w, a[7]);
}

// ---------------- edge dtype detection ----------------
__global__ void detect_i64(const void* ei, int n_nodes, int* flag) {
    const long long* p = (const long long*)ei;
    int ok = 1;
    for (int i = 0; i < 8; ++i) {
        long long v = p[i];
        if (v < 0 || v >= n_nodes) ok = 0;
    }
    *flag = ok;
}

__device__ __forceinline__ int edge_val(const int* ei32, const long long* ei64,
                                        int is64, size_t idx) {
    return is64 ? (int)ei64[idx] : ei32[idx];
}

// ---------------- CSR build: bucketed partition ----------------
__global__ __launch_bounds__(256) void pass1_hist(const int* ei32, const long long* ei64,
                                                  const int* flag, int E, int nbuck,
                                                  int* bucket_cnt) {
    __shared__ int lhist[MAXBUCK];
    for (int i = threadIdx.x; i < nbuck; i += 256) lhist[i] = 0;
    __syncthreads();
    int is64 = *flag;
    int stride = gridDim.x * 256;
    for (int e = blockIdx.x * 256 + threadIdx.x; e < E; e += stride) {
        int d = edge_val(ei32, ei64, is64, (size_t)E + e);
        atomicAdd(&lhist[d >> 8], 1);
    }
    __syncthreads();
    for (int i = threadIdx.x; i < nbuck; i += 256) {
        int c = lhist[i];
        if (c) atomicAdd(&bucket_cnt[i], c);
    }
}

__global__ __launch_bounds__(256) void bucket_scan(const int* bucket_cnt, int nbuck,
                                                   int* bucket_base, int* bucket_pos) {
    int t = threadIdx.x;
    int i0 = 2 * t, i1 = 2 * t + 1;
    int a0 = (i0 < nbuck) ? bucket_cnt[i0] : 0;
    int a1 = (i1 < nbuck) ? bucket_cnt[i1] : 0;
    int tsum = a0 + a1;
    __shared__ int sc[256];
    sc[t] = tsum;
    __syncthreads();
    for (int o = 1; o < 256; o <<= 1) {
        int x = (t >= o) ? sc[t - o] : 0;
        __syncthreads();
        if (t >= o) sc[t] += x;
        __syncthreads();
    }
    int excl = sc[t] - tsum;
    if (i0 <= nbuck) { bucket_base[i0] = excl; if (i0 < nbuck) bucket_pos[i0] = excl; }
    if (i1 <= nbuck) { bucket_base[i1] = excl + a0; if (i1 < nbuck) bucket_pos[i1] = excl + a0; }
    if (t == 255) bucket_base[nbuck] = sc[255];
}

__global__ __launch_bounds__(256) void pass2_partition(const int* ei32, const long long* ei64,
                                                       const int* flag, int E, int ept,
                                                       int nbuck, int* bucket_pos,
                                                       uint2* ebuf) {
    __shared__ int lhist[MAXBUCK];
    __shared__ int gbase[MAXBUCK];
    for (int i = threadIdx.x; i < nbuck; i += 256) lhist[i] = 0;
    __syncthreads();
    int is64 = *flag;
    int base_e = blockIdx.x * (ept * 256);
    uint2 ed[MAXEPT];
    int slot[MAXEPT];
#pragma unroll 4
    for (int i = 0; i < ept; ++i) {
        int e = base_e + i * 256 + threadIdx.x;
        if (e < E) {
            int s = edge_val(ei32, ei64, is64, (size_t)e);
            int d = edge_val(ei32, ei64, is64, (size_t)E + e);
            ed[i] = make_uint2((unsigned)s, (unsigned)d);
            slot[i] = atomicAdd(&lhist[d >> 8], 1);
        } else {
            slot[i] = -1;
        }
    }
    __syncthreads();
    for (int i = threadIdx.x; i < nbuck; i += 256) {
        int c = lhist[i];
        gbase[i] = c ? atomicAdd(&bucket_pos[i], c) : 0;
    }
    __syncthreads();
#pragma unroll 4
    for (int i = 0; i < ept; ++i) {
        if (slot[i] >= 0) {
            int b = ed[i].y >> 8;
            ebuf[gbase[b] + slot[i]] = ed[i];
        }
    }
}

__global__ __launch_bounds__(256) void pass3_finalize(const uint2* __restrict__ ebuf,
                                                      const int* __restrict__ bucket_base,
                                                      int nbuck, int N, int E,
                                                      int* __restrict__ off,
                                                      int* __restrict__ csr) {
    __shared__ int lcnt[256];
    __shared__ int lexcl[256];
    __shared__ int sc[256];
    int b = blockIdx.x;
    int t = threadIdx.x;
    int d0 = b << 8;
    int nb = N - d0; if (nb > 256) nb = 256;
    int base = bucket_base[b];
    int m = bucket_base[b + 1] - base;

    lcnt[t] = 0;
    __syncthreads();
    for (int j = t; j < m; j += 256) {
        int d = (int)ebuf[base + j].y;
        atomicAdd(&lcnt[d - d0], 1);
    }
    __syncthreads();
    int v = lcnt[t];
    sc[t] = v;
    __syncthreads();
    for (int o = 1; o < 256; o <<= 1) {
        int x = (t >= o) ? sc[t - o] : 0;
        __syncthreads();
        if (t >= o) sc[t] += x;
        __syncthreads();
    }
    int excl = sc[t] - v;
    lexcl[t] = excl;
    if (t < nb) off[d0 + t] = base + excl;
    if (b == nbuck - 1 && t == 0) off[N] = E;
    lcnt[t] = 0;   // reuse as running pos
    __syncthreads();
    for (int j = t; j < m; j += 256) {
        uint2 ed = ebuf[base + j];
        int li = (int)ed.y - d0;
        int slot = atomicAdd(&lcnt[li], 1);
        csr[base + lexcl[li] + slot] = (int)ed.x;
    }
}

// ---------------- fp32 -> bf16 conversion (x) ----------------
__global__ __launch_bounds__(256) void cvt_bf16(const float* __restrict__ in,
                                                unsigned short* __restrict__ outb,
                                                long long n8) {
    long long i = (long long)blockIdx.x * 256 + threadIdx.x;
    if (i >= n8) return;
    const float4* p = (const float4*)(in + i * 8);
    float4 a = p[0], b = p[1];
    uint4 o;
    o.x = (unsigned)f2bf(a.x) | ((unsigned)f2bf(a.y) << 16);
    o.y = (unsigned)f2bf(a.z) | ((unsigned)f2bf(a.w) << 16);
    o.z = (unsigned)f2bf(b.x) | ((unsigned)f2bf(b.y) << 16);
    o.w = (unsigned)f2bf(b.z) | ((unsigned)f2bf(b.w) << 16);
    ((uint4*)(outb))[i] = o;
}

// ---------------- weight -> MFMA B-fragment layout ----------------
__global__ __launch_bounds__(256) void mk_w1frag(const float* __restrict__ Wl,
                                                 const float* __restrict__ Wr,
                                                 uint4* __restrict__ frag) {
    int tid = blockIdx.x * 256 + threadIdx.x;   // 4096 total
    if (tid >= 4096) return;
    int fi = tid >> 6, lane = tid & 63;
    int ct = fi >> 3, ks = fi & 7;
    int k0 = ks * 32 + (lane >> 4) * 8;
    int n = ct * 16 + (lane & 15);
    unsigned short e[8];
#pragma unroll
    for (int j = 0; j < 8; ++j) {
        int k = k0 + j;
        float v = (k < 128) ? Wl[k * 128 + n] : Wr[(k - 128) * 128 + n];
        e[j] = f2bf(v);
    }
    uint4 o;
    o.x = (unsigned)e[0] | ((unsigned)e[1] << 16);
    o.y = (unsigned)e[2] | ((unsigned)e[3] << 16);
    o.z = (unsigned)e[4] | ((unsigned)e[5] << 16);
    o.w = (unsigned)e[6] | ((unsigned)e[7] << 16);
    frag[tid] = o;
}

__global__ __launch_bounds__(256) void mk_w2frag(const float* __restrict__ Wl,
                                                 const float* __restrict__ Wr,
                                                 uint4* __restrict__ frag) {
    int tid = blockIdx.x * 256 + threadIdx.x;   // 2048 total
    if (tid >= 2048) return;
    int fi = tid >> 6, lane = tid & 63;
    int ct = fi >> 2, ks = fi & 3;
    int k0 = ks * 32 + (lane >> 4) * 8;
    int n = ct * 16 + (lane & 15);
    unsigned short e[8];
#pragma unroll
    for (int j = 0; j < 8; ++j) {
        int k = k0 + j;
        float v = (n < 64) ? Wl[k * 64 + n] : Wr[k * 64 + (n - 64)];
        e[j] = f2bf(v);
    }
    uint4 o;
    o.x = (unsigned)e[0] | ((unsigned)e[1] << 16);
    o.y = (unsigned)e[2] | ((unsigned)e[3] << 16);
    o.z = (unsigned)e[4] | ((unsigned)e[5] << 16);
    o.w = (unsigned)e[6] | ((unsigned)e[7] << 16);
    frag[tid] = o;
}

// ---------------- mean aggregation, D=128 bf16, 16B/lane ----------------
// one wave per node; l16 = uint4 slot (8 dims), quad = edge within group of 4.
// main loop: 8 edges / iter, 2 independent 1KB loads.
__global__ __launch_bounds__(256) void agg_mean128_bf(const unsigned short* __restrict__ Xb,
                                                      const int* __restrict__ off,
                                                      const int* __restrict__ csr,
                                                      unsigned short* __restrict__ outb,
                                                      int n_nodes) {
    int node = blockIdx.x * 4 + (threadIdx.x >> 6);
    if (node >= n_nodes) return;
    int lane = threadIdx.x & 63;
    int quad = lane >> 4;
    int l16 = lane & 15;
    int s0 = off[node], s1 = off[node + 1];
    int deg = s1 - s0;
    float a0[8] = {0.f, 0.f, 0.f, 0.f, 0.f, 0.f, 0.f, 0.f};
    float a1[8] = {0.f, 0.f, 0.f, 0.f, 0.f, 0.f, 0.f, 0.f};
    int j = s0;
    for (; j + 8 <= s1; j += 8) {
        int p0 = csr[j + quad];
        int p1 = csr[j + 4 + quad];
        uint4 v0 = ((const uint4*)(Xb + (size_t)p0 * 128))[l16];
        uint4 v1 = ((const uint4*)(Xb + (size_t)p1 * 128))[l16];
        unpack8_add(v0, a0);
        unpack8_add(v1, a1);
    }
    if (j + 4 <= s1) {
        int p = csr[j + quad];
        uint4 v = ((const uint4*)(Xb + (size_t)p * 128))[l16];
        unpack8_add(v, a0);
        j += 4;
    }
    if (j < s1) {  // masked tail, 1..3 edges
        int jj = j + quad;
        int p = csr[(jj < s1) ? jj : (s1 - 1)];
        float w = (jj < s1) ? 1.0f : 0.0f;
        uint4 v = ((const uint4*)(Xb + (size_t)p * 128))[l16];
        unpack8_fma(v, w, a1);
    }
    float r[8];
#pragma unroll
    for (int k = 0; k < 8; ++k) r[k] = a0[k] + a1[k];
#pragma unroll
    for (int k = 0; k < 8; ++k) r[k] += __shfl(r[k], lane ^ 16);
#pragma unroll
    for (int k = 0; k < 8; ++k) r[k] += __shfl(r[k], lane ^ 32);
    float inv = (deg > 0) ? 1.0f / (float)deg : 0.0f;
    if (quad == 0) {
        uint4 o;
        o.x = (unsigned)f2bf(r[0] * inv) | ((unsigned)f2bf(r[1] * inv) << 16);
        o.y = (unsigned)f2bf(r[2] * inv) | ((unsigned)f2bf(r[3] * inv) << 16);
        o.z = (unsigned)f2bf(r[4] * inv) | ((unsigned)f2bf(r[5] * inv) << 16);
        o.w = (unsigned)f2bf(r[6] * inv) | ((unsigned)f2bf(r[7] * inv) << 16);
        ((uint4*)(outb + (size_t)node * 128))[l16] = o;
    }
}

// ---------------- mean aggregation, D=64 bf16, 16B/lane, epilogue +w2 -------
// l8 = uint4 slot (8 dims), oct = edge within group of 8. 16 edges / iter.
__global__ __launch_bounds__(256) void agg_mean64_bf_ep(const unsigned short* __restrict__ Zb,
                                                        const float* __restrict__ Wadd,
                                                        const int* __restrict__ off,
                                                        const int* __restrict__ csr,
                                                        float* __restrict__ out,
                                                        int n_nodes) {
    int node = blockIdx.x * 4 + (threadIdx.x >> 6);
    if (node >= n_nodes) return;
    int lane = threadIdx.x & 63;
    int oct = lane >> 3;
    int l8 = lane & 7;
    int s0 = off[node], s1 = off[node + 1];
    int deg = s1 - s0;
    float a0[8] = {0.f, 0.f, 0.f, 0.f, 0.f, 0.f, 0.f, 0.f};
    float a1[8] = {0.f, 0.f, 0.f, 0.f, 0.f, 0.f, 0.f, 0.f};
    int j = s0;
    for (; j + 16 <= s1; j += 16) {
        int p0 = csr[j + oct];
        int p1 = csr[j + 8 + oct];
        uint4 v0 = ((const uint4*)(Zb + (size_t)p0 * 64))[l8];
        uint4 v1 = ((const uint4*)(Zb + (size_t)p1 * 64))[l8];
        unpack8_add(v0, a0);
        unpack8_add(v1, a1);
    }
    if (j + 8 <= s1) {
        int p = csr[j + oct];
        uint4 v = ((const uint4*)(Zb + (size_t)p * 64))[l8];
        unpack8_add(v, a0);
        j += 8;
    }
    if (j < s1) {  // masked tail, 1..7 edges
        int jj = j + oct;
        int p = csr[(jj < s1) ? jj : (s1 - 1)];
        float w = (jj < s1) ? 1.0f : 0.0f;
        uint4 v = ((const uint4*)(Zb + (size_t)p * 64))[l8];
        unpack8_fma(v, w, a1);
    }
    float r[8];
#pragma unroll
    for (int k = 0; k < 8; ++k) r[k] = a0[k] + a1[k];
#pragma unroll
    for (int k = 0; k < 8; ++k) r[k] += __shfl(r[k], lane ^ 8);
#pragma unroll
    for (int k = 0; k < 8; ++k) r[k] += __shfl(r[k], lane ^ 16);
#pragma unroll
    for (int k = 0; k < 8; ++k) r[k] += __shfl(r[k], lane ^ 32);
    float inv = (deg > 0) ? 1.0f / (float)deg : 0.0f;
    if (oct == 0) {
        const float4* wp = (const float4*)(Wadd + (size_t)node * 64 + l8 * 8);
        float4 w0 = wp[0], w1 = wp[1];
        float4 o0, o1;
        o0.x = r[0] * inv + w0.x; o0.y = r[1] * inv + w0.y;
        o0.z = r[2] * inv + w0.z; o0.w = r[3] * inv + w0.w;
        o1.x = r[4] * inv + w1.x; o1.y = r[5] * inv + w1.y;
        o1.z = r[6] * inv + w1.z; o1.w = r[7] * inv + w1.w;
        float4* op = (float4*)(out + (size_t)node * 64 + l8 * 8);
        op[0] = o0; op[1] = o1;
    }
}

// ---------------- GEMM1 (MFMA): hb = relu([mean|x] @ Wcat + b1), K=256 -------
__global__ __launch_bounds__(256, 2) void gemm1_mfma(const unsigned short* __restrict__ meanb,
                                                     const unsigned short* __restrict__ xb,
                                                     const uint4* __restrict__ wfrag,
                                                     const float* __restrict__ bias,
                                                     unsigned short* __restrict__ hb,
                                                     int nrows) {
    __shared__ uint4 sW[4096];   // 64 KB
    for (int i = threadIdx.x; i < 4096; i += 256) sW[i] = wfrag[i];
    __syncthreads();
    const int wid = threadIdx.x >> 6, lane = threadIdx.x & 63;
    const int quad = lane >> 4, l16 = lane & 15;
    const int m0 = blockIdx.x * 128 + wid * 32;

    bf16x8 af[2][8];
#pragma unroll
    for (int mt = 0; mt < 2; ++mt) {
        int row = m0 + mt * 16 + l16;
        row = (row < nrows) ? row : (nrows - 1);
        const uint4* mrow = (const uint4*)(meanb + (size_t)row * 128);
        const uint4* xrow = (const uint4*)(xb + (size_t)row * 128);
#pragma unroll
        for (int ks = 0; ks < 4; ++ks) {
            af[mt][ks]     = __builtin_bit_cast(bf16x8, mrow[ks * 4 + quad]);
            af[mt][ks + 4] = __builtin_bit_cast(bf16x8, xrow[ks * 4 + quad]);
        }
    }

    f32x4 acc[2][8];
#pragma unroll
    for (int mt = 0; mt < 2; ++mt)
#pragma unroll
        for (int ct = 0; ct < 8; ++ct) acc[mt][ct] = (f32x4){0.f, 0.f, 0.f, 0.f};

#pragma unroll
    for (int ct = 0; ct < 8; ++ct) {
#pragma unroll
        for (int ks = 0; ks < 8; ++ks) {
            bf16x8 bf = __builtin_bit_cast(bf16x8, sW[(ct * 8 + ks) * 64 + lane]);
            acc[0][ct] = __builtin_amdgcn_mfma_f32_16x16x32_bf16(af[0][ks], bf, acc[0][ct], 0, 0, 0);
            acc[1][ct] = __builtin_amdgcn_mfma_f32_16x16x32_bf16(af[1][ks], bf, acc[1][ct], 0, 0, 0);
        }
    }

#pragma unroll
    for (int mt = 0; mt < 2; ++mt) {
#pragma unroll
        for (int ct = 0; ct < 8; ++ct) {
            int col = ct * 16 + l16;
            float bb = bias[col];
#pragma unroll
            for (int r = 0; r < 4; ++r) {
                int row = m0 + mt * 16 + quad * 4 + r;
                if (row < nrows) {
                    float v = fmaxf(acc[mt][ct][r] + bb, 0.f);
                    hb[(size_t)row * 128 + col] = f2bf(v);
                }
            }
        }
    }
}

// ---------------- GEMM2 (MFMA): z2 = hb@W2_l (bf16), w2 = hb@W2_r + b2 (fp32)
__global__ __launch_bounds__(256, 2) void gemm2_mfma(const unsigned short* __restrict__ hb,
                                                     const uint4* __restrict__ wfrag,
                                                     const float* __restrict__ bias,
                                                     unsigned short* __restrict__ z2,
                                                     float* __restrict__ w2,
                                                     int nrows) {
    __shared__ uint4 sW[2048];   // 32 KB
    for (int i = threadIdx.x; i < 2048; i += 256) sW[i] = wfrag[i];
    __syncthreads();
    const int wid = threadIdx.x >> 6, lane = threadIdx.x & 63;
    const int quad = lane >> 4, l16 = lane & 15;
    const int m0 = blockIdx.x * 128 + wid * 32;

    bf16x8 af[2][4];
#pragma unroll
    for (int mt = 0; mt < 2; ++mt) {
        int row = m0 + mt * 16 + l16;
        row = (row < nrows) ? row : (nrows - 1);
        const uint4* hrow = (const uint4*)(hb + (size_t)row * 128);
#pragma unroll
        for (int ks = 0; ks < 4; ++ks)
            af[mt][ks] = __builtin_bit_cast(bf16x8, hrow[ks * 4 + quad]);
    }

    f32x4 acc[2][8];
#pragma unroll
    for (int mt = 0; mt < 2; ++mt)
#pragma unroll
        for (int ct = 0; ct < 8; ++ct) acc[mt][ct] = (f32x4){0.f, 0.f, 0.f, 0.f};

#pragma unroll
    for (int ct = 0; ct < 8; ++ct) {
#pragma unroll
        for (int ks = 0; ks < 4; ++ks) {
            bf16x8 bf = __builtin_bit_cast(bf16x8, sW[(ct * 4 + ks) * 64 + lane]);
            acc[0][ct] = __builtin_amdgcn_mfma_f32_16x16x32_bf16(af[0][ks], bf, acc[0][ct], 0, 0, 0);
            acc[1][ct] = __builtin_amdgcn_mfma_f32_16x16x32_bf16(af[1][ks], bf, acc[1][ct], 0, 0, 0);
        }
    }

#pragma unroll
    for (int mt = 0; mt < 2; ++mt) {
#pragma unroll
        for (int ct = 0; ct < 8; ++ct) {
            int col = ct * 16 + l16;
#pragma unroll
            for (int r = 0; r < 4; ++r) {
                int row = m0 + mt * 16 + quad * 4 + r;
                if (row < nrows) {
                    if (col < 64) {
                        z2[(size_t)row * 64 + col] = f2bf(acc[mt][ct][r]);
                    } else {
                        w2[(size_t)row * 64 + (col - 64)] = acc[mt][ct][r] + bias[col - 64];
                    }
                }
            }
        }
    }
}

extern "C" void kernel_launch(void* const* d_in, const int* in_sizes, int n_in,
                              void* d_out, int out_size, void* d_ws, size_t ws_size,
                              hipStream_t stream) {
    const float* x    = (const float*)d_in[0];
    const float* W1_l = (const float*)d_in[1];
    const float* b1   = (const float*)d_in[2];
    const float* W1_r = (const float*)d_in[3];
    const float* W2_l = (const float*)d_in[4];
    const float* b2   = (const float*)d_in[5];
    const float* W2_r = (const float*)d_in[6];
    const void*  ei   = d_in[7];
    float* out = (float*)d_out;

    const int N = in_sizes[0] / 128;      // 100000
    const int E = in_sizes[7] / 2;        // 1600000
    const int nbuck = (N + 255) >> 8;     // 391

    // workspace layout
    uintptr_t base = (uintptr_t)d_ws;
    int* flag = (int*)base;                                   // 1 int
    int* bucket_cnt  = (int*)(base + 64);                     // nbuck
    int* bucket_base = bucket_cnt + MAXBUCK;                  // nbuck+1
    int* bucket_pos  = bucket_base + MAXBUCK + 1;             // nbuck
    int* off = (int*)(base + 4096 + 3 * MAXBUCK * 4);
    off = (int*)(((uintptr_t)off + 255) & ~(uintptr_t)255);   // N+1
    int* csr = off + (N + 1);                                 // E
    uintptr_t p = ((uintptr_t)(csr + E) + 255) & ~(uintptr_t)255;
    unsigned short* xb    = (unsigned short*)p; p += (size_t)N * 128 * 2;   // bf16 x
    unsigned short* meanb = (unsigned short*)p; p += (size_t)N * 128 * 2;   // bf16 mean / z2 / ebuf
    unsigned short* hb    = (unsigned short*)p; p += (size_t)N * 128 * 2;   // bf16 h
    uint4* w1frag = (uint4*)p; p += 4096 * 16;
    uint4* w2frag = (uint4*)p; p += 2048 * 16;
    uint2* ebuf = (uint2*)meanb;           // dead before agg_mean128_bf writes meanb
    unsigned short* z2 = meanb;            // meanb dead after gemm1
    float* w2 = (float*)xb;                // xb dead after gemm1

    const int* ei32 = (const int*)ei;
    const long long* ei64 = (const long long*)ei;

    hipMemsetAsync(bucket_cnt, 0, sizeof(int) * MAXBUCK, stream);

    detect_i64<<<1, 1, 0, stream>>>(ei, N, flag);

    // conversions (independent of CSR)
    long long n8 = (long long)N * 128 / 8;
    cvt_bf16<<<(int)((n8 + 255) / 256), 256, 0, stream>>>(x, xb, n8);
    mk_w1frag<<<16, 256, 0, stream>>>(W1_l, W1_r, w1frag);
    mk_w2frag<<<8, 256, 0, stream>>>(W2_l, W2_r, w2frag);

    // CSR build
    pass1_hist<<<512, 256, 0, stream>>>(ei32, ei64, flag, E, nbuck, bucket_cnt);
    bucket_scan<<<1, 256, 0, stream>>>(bucket_cnt, nbuck, bucket_base, bucket_pos);
    int ept = (E + 512 * 256 - 1) / (512 * 256);   // 13 for E=1.6M (<= MAXEPT)
    pass2_partition<<<512, 256, 0, stream>>>(ei32, ei64, flag, E, ept, nbuck,
                                             bucket_pos, ebuf);
    pass3_finalize<<<nbuck, 256, 0, stream>>>(ebuf, bucket_base, nbuck, N, E, off, csr);

    int ablocks = (N + 3) / 4;
    int gblocks = (N + 127) / 128;

    // layer 1
    agg_mean128_bf<<<ablocks, 256, 0, stream>>>(xb, off, csr, meanb, N);
    gemm1_mfma<<<gblocks, 256, 0, stream>>>(meanb, xb, w1frag, b1, hb, N);

    // layer 2 (commuted)
    gemm2_mfma<<<gblocks, 256, 0, stream>>>(hb, w2frag, b2, z2, w2, N);
    agg_mean64_bf_ep<<<ablocks, 256, 0, stream>>>(z2, w2, off, csr, out, N);
}

// Round 7
// 331.228 us; speedup vs baseline: 2.4053x; 1.0153x over previous
//
#include <hip/hip_runtime.h>
#include <hip/hip_bf16.h>
#include <cstdint>

// GraphSAGE 2-layer, bf16 features + fp32 accumulate, MFMA GEMMs.
// Layer1: h   = relu([mean_agg(x) | x] @ [W1_l; W1_r] + b1)   (K=256 MFMA GEMM)
// Layer2: out = mean_agg(h @ W2_l) + h @ W2_r + b2            (agg commutes w/ linear)
// CSR via dst-bucketed partition (LDS atomics only, contiguous csr writes).
// Aggs: 16B/lane gathers, f32x2 packed accumulate (v_pk_add_f32), 4 loads in flight.
// NOTE: fdot2_f32_bf16 was tried in R6 and gave WRONG results on gfx950 — do not use.

typedef __bf16 bf16x8 __attribute__((ext_vector_type(8)));
typedef float f32x4 __attribute__((ext_vector_type(4)));
typedef float f32x2 __attribute__((ext_vector_type(2)));

#define MAXBUCK 400   // >= ceil(100352/256); N=100000 -> 391 buckets
#define MAXEPT 16
#define HISTB 512     // hist blocks inside prep kernel
#define P2B 512       // pass2 blocks

__device__ __forceinline__ unsigned short f2bf(float f) {
    union { float f; unsigned int u; } v; v.f = f;
    unsigned int u = v.u;
    unsigned int r = ((u >> 16) & 1u) + 0x7fffu;
    return (unsigned short)((u + r) >> 16);
}

// unpack uint (2 bf16) -> f32x2 {lo, hi}
__device__ __forceinline__ f32x2 up2(unsigned int u) {
    uint2 t; t.x = u << 16; t.y = u & 0xffff0000u;
    return __builtin_bit_cast(f32x2, t);
}
// accumulate 8 bf16 elements of v into a[0..4) pairs
__device__ __forceinline__ void accp(const uint4& v, f32x2* a) {
    a[0] += up2(v.x);
    a[1] += up2(v.y);
    a[2] += up2(v.z);
    a[3] += up2(v.w);
}
__device__ __forceinline__ void accpw(const uint4& v, float w, f32x2* a) {
    a[0] += up2(v.x) * w;
    a[1] += up2(v.y) * w;
    a[2] += up2(v.z) * w;
    a[3] += up2(v.w) * w;
}

__device__ __forceinline__ int edge_val(const int* ei32, const long long* ei64,
                                        int is64, size_t idx) {
    return is64 ? (int)ei64[idx] : ei32[idx];
}

// ---------------- detect edge dtype + zero bucket counters ----------------
__global__ __launch_bounds__(256) void detect_zero(const void* ei, int n_nodes,
                                                   int* flag, int* bucket_cnt) {
    for (int i = threadIdx.x; i < MAXBUCK; i += 256) bucket_cnt[i] = 0;
    if (threadIdx.x == 0) {
        const long long* p = (const long long*)ei;
        int ok = 1;
        for (int i = 0; i < 8; ++i) {
            long long v = p[i];
            if (v < 0 || v >= n_nodes) ok = 0;
        }
        *flag = ok;
    }
}

// ---------------- fused prep: cvt x->bf16 | w1 frags | w2 frags | coarse hist
__global__ __launch_bounds__(256) void prep_kernel(const float* __restrict__ x,
                                                   unsigned short* __restrict__ xb,
                                                   long long n8, int ncvt,
                                                   const float* __restrict__ W1l,
                                                   const float* __restrict__ W1r,
                                                   uint4* __restrict__ w1frag,
                                                   const float* __restrict__ W2l,
                                                   const float* __restrict__ W2r,
                                                   uint4* __restrict__ w2frag,
                                                   const int* ei32, const long long* ei64,
                                                   const int* flag, int E, int nbuck,
                                                   int* bucket_cnt) {
    int b = blockIdx.x;
    if (b < ncvt) {
        long long i = (long long)b * 256 + threadIdx.x;
        if (i >= n8) return;
        const float4* p = (const float4*)(x + i * 8);
        float4 a = p[0], c = p[1];
        uint4 o;
        o.x = (unsigned)f2bf(a.x) | ((unsigned)f2bf(a.y) << 16);
        o.y = (unsigned)f2bf(a.z) | ((unsigned)f2bf(a.w) << 16);
        o.z = (unsigned)f2bf(c.x) | ((unsigned)f2bf(c.y) << 16);
        o.w = (unsigned)f2bf(c.z) | ((unsigned)f2bf(c.w) << 16);
        ((uint4*)(xb))[i] = o;
        return;
    }
    if (b < ncvt + 16) {   // W1 frags: Wcat[256][128] = [W1_l; W1_r], 64 frags
        int tid = (b - ncvt) * 256 + threadIdx.x;   // 4096
        int fi = tid >> 6, lane = tid & 63;
        int ct = fi >> 3, ks = fi & 7;
        int k0 = ks * 32 + (lane >> 4) * 8;
        int n = ct * 16 + (lane & 15);
        unsigned short e[8];
#pragma unroll
        for (int j = 0; j < 8; ++j) {
            int k = k0 + j;
            float v = (k < 128) ? W1l[k * 128 + n] : W1r[(k - 128) * 128 + n];
            e[j] = f2bf(v);
        }
        uint4 o;
        o.x = (unsigned)e[0] | ((unsigned)e[1] << 16);
        o.y = (unsigned)e[2] | ((unsigned)e[3] << 16);
        o.z = (unsigned)e[4] | ((unsigned)e[5] << 16);
        o.w = (unsigned)e[6] | ((unsigned)e[7] << 16);
        w1frag[tid] = o;
        return;
    }
    if (b < ncvt + 16 + 8) {  // W2 frags: Wcat2[128][128] = [W2_l | W2_r], 32 frags
        int tid = (b - ncvt - 16) * 256 + threadIdx.x;   // 2048
        int fi = tid >> 6, lane = tid & 63;
        int ct = fi >> 2, ks = fi & 3;
        int k0 = ks * 32 + (lane >> 4) * 8;
        int n = ct * 16 + (lane & 15);
        unsigned short e[8];
#pragma unroll
        for (int j = 0; j < 8; ++j) {
            int k = k0 + j;
            float v = (n < 64) ? W2l[k * 64 + n] : W2r[k * 64 + (n - 64)];
            e[j] = f2bf(v);
        }
        uint4 o;
        o.x = (unsigned)e[0] | ((unsigned)e[1] << 16);
        o.y = (unsigned)e[2] | ((unsigned)e[3] << 16);
        o.z = (unsigned)e[4] | ((unsigned)e[5] << 16);
        o.w = (unsigned)e[6] | ((unsigned)e[7] << 16);
        w2frag[tid] = o;
        return;
    }
    // coarse hist of dst>>8
    __shared__ int lhist[MAXBUCK];
    for (int i = threadIdx.x; i < nbuck; i += 256) lhist[i] = 0;
    __syncthreads();
    int is64 = *flag;
    int hb = b - (ncvt + 24);
    int stride = HISTB * 256;
    for (int e = hb * 256 + threadIdx.x; e < E; e += stride) {
        int d = edge_val(ei32, ei64, is64, (size_t)E + e);
        atomicAdd(&lhist[d >> 8], 1);
    }
    __syncthreads();
    for (int i = threadIdx.x; i < nbuck; i += 256) {
        int c = lhist[i];
        if (c) atomicAdd(&bucket_cnt[i], c);
    }
}

// ---------------- CSR build ----------------
__global__ __launch_bounds__(256) void bucket_scan(const int* bucket_cnt, int nbuck,
                                                   int* bucket_base, int* bucket_pos) {
    int t = threadIdx.x;
    int i0 = 2 * t, i1 = 2 * t + 1;
    int a0 = (i0 < nbuck) ? bucket_cnt[i0] : 0;
    int a1 = (i1 < nbuck) ? bucket_cnt[i1] : 0;
    int tsum = a0 + a1;
    __shared__ int sc[256];
    sc[t] = tsum;
    __syncthreads();
    for (int o = 1; o < 256; o <<= 1) {
        int x = (t >= o) ? sc[t - o] : 0;
        __syncthreads();
        if (t >= o) sc[t] += x;
        __syncthreads();
    }
    int excl = sc[t] - tsum;
    if (i0 <= nbuck) { bucket_base[i0] = excl; if (i0 < nbuck) bucket_pos[i0] = excl; }
    if (i1 <= nbuck) { bucket_base[i1] = excl + a0; if (i1 < nbuck) bucket_pos[i1] = excl + a0; }
    if (t == 255) bucket_base[nbuck] = sc[255];
}

__global__ __launch_bounds__(256) void pass2_partition(const int* ei32, const long long* ei64,
                                                       const int* flag, int E, int ept,
                                                       int nbuck, int* bucket_pos,
                                                       uint2* ebuf) {
    __shared__ int lhist[MAXBUCK];
    __shared__ int gbase[MAXBUCK];
    for (int i = threadIdx.x; i < nbuck; i += 256) lhist[i] = 0;
    __syncthreads();
    int is64 = *flag;
    int base_e = blockIdx.x * (ept * 256);
    uint2 ed[MAXEPT];
    int slot[MAXEPT];
#pragma unroll 4
    for (int i = 0; i < ept; ++i) {
        int e = base_e + i * 256 + threadIdx.x;
        if (e < E) {
            int s = edge_val(ei32, ei64, is64, (size_t)e);
            int d = edge_val(ei32, ei64, is64, (size_t)E + e);
            ed[i] = make_uint2((unsigned)s, (unsigned)d);
            slot[i] = atomicAdd(&lhist[d >> 8], 1);
        } else {
            slot[i] = -1;
        }
    }
    __syncthreads();
    for (int i = threadIdx.x; i < nbuck; i += 256) {
        int c = lhist[i];
        gbase[i] = c ? atomicAdd(&bucket_pos[i], c) : 0;
    }
    __syncthreads();
#pragma unroll 4
    for (int i = 0; i < ept; ++i) {
        if (slot[i] >= 0) {
            int b = ed[i].y >> 8;
            ebuf[gbase[b] + slot[i]] = ed[i];
        }
    }
}

__global__ __launch_bounds__(256) void pass3_finalize(const uint2* __restrict__ ebuf,
                                                      const int* __restrict__ bucket_base,
                                                      int nbuck, int N, int E,
                                                      int* __restrict__ off,
                                                      int* __restrict__ csr) {
    __shared__ int lcnt[256];
    __shared__ int lexcl[256];
    __shared__ int sc[256];
    int b = blockIdx.x;
    int t = threadIdx.x;
    int d0 = b << 8;
    int nb = N - d0; if (nb > 256) nb = 256;
    int base = bucket_base[b];
    int m = bucket_base[b + 1] - base;

    lcnt[t] = 0;
    __syncthreads();
    for (int j = t; j < m; j += 256) {
        int d = (int)ebuf[base + j].y;
        atomicAdd(&lcnt[d - d0], 1);
    }
    __syncthreads();
    int v = lcnt[t];
    sc[t] = v;
    __syncthreads();
    for (int o = 1; o < 256; o <<= 1) {
        int x = (t >= o) ? sc[t - o] : 0;
        __syncthreads();
        if (t >= o) sc[t] += x;
        __syncthreads();
    }
    int excl = sc[t] - v;
    lexcl[t] = excl;
    if (t < nb) off[d0 + t] = base + excl;
    if (b == nbuck - 1 && t == 0) off[N] = E;
    lcnt[t] = 0;   // reuse as running pos
    __syncthreads();
    for (int j = t; j < m; j += 256) {
        uint2 ed = ebuf[base + j];
        int li = (int)ed.y - d0;
        int slot = atomicAdd(&lcnt[li], 1);
        csr[base + lexcl[li] + slot] = (int)ed.x;
    }
}

// ---------------- mean aggregation, D=128 bf16, 16B/lane ----------------
// one wave per node; l16 = uint4 slot (8 dims), quad = edge within group of 4.
// main loop: 16 edges / iter, 4 independent 1KB loads in flight.
__global__ __launch_bounds__(256) void agg_mean128_bf(const unsigned short* __restrict__ Xb,
                                                      const int* __restrict__ off,
                                                      const int* __restrict__ csr,
                                                      unsigned short* __restrict__ outb,
                                                      int n_nodes) {
    int node = blockIdx.x * 4 + (threadIdx.x >> 6);
    if (node >= n_nodes) return;
    int lane = threadIdx.x & 63;
    int quad = lane >> 4;
    int l16 = lane & 15;
    int s0 = off[node], s1 = off[node + 1];
    int deg = s1 - s0;
    f32x2 A[4][4];
#pragma unroll
    for (int s = 0; s < 4; ++s)
#pragma unroll
        for (int k = 0; k < 4; ++k) A[s][k] = (f32x2){0.f, 0.f};
    int j = s0;
    for (; j + 16 <= s1; j += 16) {
        int p0 = csr[j + quad];
        int p1 = csr[j + 4 + quad];
        int p2 = csr[j + 8 + quad];
        int p3 = csr[j + 12 + quad];
        uint4 v0 = ((const uint4*)(Xb + (size_t)p0 * 128))[l16];
        uint4 v1 = ((const uint4*)(Xb + (size_t)p1 * 128))[l16];
        uint4 v2 = ((const uint4*)(Xb + (size_t)p2 * 128))[l16];
        uint4 v3 = ((const uint4*)(Xb + (size_t)p3 * 128))[l16];
        accp(v0, A[0]);
        accp(v1, A[1]);
        accp(v2, A[2]);
        accp(v3, A[3]);
    }
    if (j + 8 <= s1) {
        int p0 = csr[j + quad];
        int p1 = csr[j + 4 + quad];
        uint4 v0 = ((const uint4*)(Xb + (size_t)p0 * 128))[l16];
        uint4 v1 = ((const uint4*)(Xb + (size_t)p1 * 128))[l16];
        accp(v0, A[0]);
        accp(v1, A[1]);
        j += 8;
    }
    if (j + 4 <= s1) {
        int p = csr[j + quad];
        uint4 v = ((const uint4*)(Xb + (size_t)p * 128))[l16];
        accp(v, A[2]);
        j += 4;
    }
    if (j < s1) {  // masked tail, 1..3 edges
        int jj = j + quad;
        int p = csr[(jj < s1) ? jj : (s1 - 1)];
        float w = (jj < s1) ? 1.0f : 0.0f;
        uint4 v = ((const uint4*)(Xb + (size_t)p * 128))[l16];
        accpw(v, w, A[3]);
    }
    float r[8];
#pragma unroll
    for (int k = 0; k < 4; ++k) {
        f32x2 s = (A[0][k] + A[1][k]) + (A[2][k] + A[3][k]);
        r[2 * k] = s.x;
        r[2 * k + 1] = s.y;
    }
#pragma unroll
    for (int k = 0; k < 8; ++k) r[k] += __shfl(r[k], lane ^ 16);
#pragma unroll
    for (int k = 0; k < 8; ++k) r[k] += __shfl(r[k], lane ^ 32);
    float inv = (deg > 0) ? 1.0f / (float)deg : 0.0f;
    if (quad == 0) {
        uint4 o;
        o.x = (unsigned)f2bf(r[0] * inv) | ((unsigned)f2bf(r[1] * inv) << 16);
        o.y = (unsigned)f2bf(r[2] * inv) | ((unsigned)f2bf(r[3] * inv) << 16);
        o.z = (unsigned)f2bf(r[4] * inv) | ((unsigned)f2bf(r[5] * inv) << 16);
        o.w = (unsigned)f2bf(r[6] * inv) | ((unsigned)f2bf(r[7] * inv) << 16);
        ((uint4*)(outb + (size_t)node * 128))[l16] = o;
    }
}

// ---------------- mean aggregation, D=64 bf16, 16B/lane, epilogue +w2 -------
// l8 = uint4 slot (8 dims), oct = edge within group of 8. 16 edges / iter.
__global__ __launch_bounds__(256) void agg_mean64_bf_ep(const unsigned short* __restrict__ Zb,
                                                        const float* __restrict__ Wadd,
                                                        const int* __restrict__ off,
                                                        const int* __restrict__ csr,
                                                        float* __restrict__ out,
                                                        int n_nodes) {
    int node = blockIdx.x * 4 + (threadIdx.x >> 6);
    if (node >= n_nodes) return;
    int lane = threadIdx.x & 63;
    int oct = lane >> 3;
    int l8 = lane & 7;
    int s0 = off[node], s1 = off[node + 1];
    int deg = s1 - s0;
    f32x2 A0[4], A1[4];
#pragma unroll
    for (int k = 0; k < 4; ++k) { A0[k] = (f32x2){0.f, 0.f}; A1[k] = (f32x2){0.f, 0.f}; }
    int j = s0;
    for (; j + 16 <= s1; j += 16) {
        int p0 = csr[j + oct];
        int p1 = csr[j + 8 + oct];
        uint4 v0 = ((const uint4*)(Zb + (size_t)p0 * 64))[l8];
        uint4 v1 = ((const uint4*)(Zb + (size_t)p1 * 64))[l8];
        accp(v0, A0);
        accp(v1, A1);
    }
    if (j + 8 <= s1) {
        int p = csr[j + oct];
        uint4 v = ((const uint4*)(Zb + (size_t)p * 64))[l8];
        accp(v, A0);
        j += 8;
    }
    if (j < s1) {  // masked tail, 1..7 edges
        int jj = j + oct;
        int p = csr[(jj < s1) ? jj : (s1 - 1)];
        float w = (jj < s1) ? 1.0f : 0.0f;
        uint4 v = ((const uint4*)(Zb + (size_t)p * 64))[l8];
        accpw(v, w, A1);
    }
    float r[8];
#pragma unroll
    for (int k = 0; k < 4; ++k) {
        f32x2 s = A0[k] + A1[k];
        r[2 * k] = s.x;
        r[2 * k + 1] = s.y;
    }
#pragma unroll
    for (int k = 0; k < 8; ++k) r[k] += __shfl(r[k], lane ^ 8);
#pragma unroll
    for (int k = 0; k < 8; ++k) r[k] += __shfl(r[k], lane ^ 16);
#pragma unroll
    for (int k = 0; k < 8; ++k) r[k] += __shfl(r[k], lane ^ 32);
    float inv = (deg > 0) ? 1.0f / (float)deg : 0.0f;
    if (oct == 0) {
        const float4* wp = (const float4*)(Wadd + (size_t)node * 64 + l8 * 8);
        float4 w0 = wp[0], w1 = wp[1];
        float4 o0, o1;
        o0.x = r[0] * inv + w0.x; o0.y = r[1] * inv + w0.y;
        o0.z = r[2] * inv + w0.z; o0.w = r[3] * inv + w0.w;
        o1.x = r[4] * inv + w1.x; o1.y = r[5] * inv + w1.y;
        o1.z = r[6] * inv + w1.z; o1.w = r[7] * inv + w1.w;
        float4* op = (float4*)(out + (size_t)node * 64 + l8 * 8);
        op[0] = o0; op[1] = o1;
    }
}

// ---------------- GEMM1 (MFMA): hb = relu([mean|x] @ Wcat + b1), K=256 -------
__global__ __launch_bounds__(256, 2) void gemm1_mfma(const unsigned short* __restrict__ meanb,
                                                     const unsigned short* __restrict__ xb,
                                                     const uint4* __restrict__ wfrag,
                                                     const float* __restrict__ bias,
                                                     unsigned short* __restrict__ hb,
                                                     int nrows) {
    __shared__ uint4 sW[4096];   // 64 KB
    for (int i = threadIdx.x; i < 4096; i += 256) sW[i] = wfrag[i];
    __syncthreads();
    const int wid = threadIdx.x >> 6, lane = threadIdx.x & 63;
    const int quad = lane >> 4, l16 = lane & 15;
    const int m0 = blockIdx.x * 128 + wid * 32;

    bf16x8 af[2][8];
#pragma unroll
    for (int mt = 0; mt < 2; ++mt) {
        int row = m0 + mt * 16 + l16;
        row = (row < nrows) ? row : (nrows - 1);
        const uint4* mrow = (const uint4*)(meanb + (size_t)row * 128);
        const uint4* xrow = (const uint4*)(xb + (size_t)row * 128);
#pragma unroll
        for (int ks = 0; ks < 4; ++ks) {
            af[mt][ks]     = __builtin_bit_cast(bf16x8, mrow[ks * 4 + quad]);
            af[mt][ks + 4] = __builtin_bit_cast(bf16x8, xrow[ks * 4 + quad]);
        }
    }

    f32x4 acc[2][8];
#pragma unroll
    for (int mt = 0; mt < 2; ++mt)
#pragma unroll
        for (int ct = 0; ct < 8; ++ct) acc[mt][ct] = (f32x4){0.f, 0.f, 0.f, 0.f};

#pragma unroll
    for (int ct = 0; ct < 8; ++ct) {
#pragma unroll
        for (int ks = 0; ks < 8; ++ks) {
            bf16x8 bf = __builtin_bit_cast(bf16x8, sW[(ct * 8 + ks) * 64 + lane]);
            acc[0][ct] = __builtin_amdgcn_mfma_f32_16x16x32_bf16(af[0][ks], bf, acc[0][ct], 0, 0, 0);
            acc[1][ct] = __builtin_amdgcn_mfma_f32_16x16x32_bf16(af[1][ks], bf, acc[1][ct], 0, 0, 0);
        }
    }

#pragma unroll
    for (int mt = 0; mt < 2; ++mt) {
#pragma unroll
        for (int ct = 0; ct < 8; ++ct) {
            int col = ct * 16 + l16;
            float bb = bias[col];
#pragma unroll
            for (int r = 0; r < 4; ++r) {
                int row = m0 + mt * 16 + quad * 4 + r;
                if (row < nrows) {
                    float v = fmaxf(acc[mt][ct][r] + bb, 0.f);
                    hb[(size_t)row * 128 + col] = f2bf(v);
                }
            }
        }
    }
}

// ---------------- GEMM2 (MFMA): z2 = hb@W2_l (bf16), w2 = hb@W2_r + b2 (fp32)
__global__ __launch_bounds__(256, 2) void gemm2_mfma(const unsigned short* __restrict__ hb,
                                                     const uint4* __restrict__ wfrag,
                                                     const float* __restrict__ bias,
                                                     unsigned short* __restrict__ z2,
                                                     float* __restrict__ w2,
                                                     int nrows) {
    __shared__ uint4 sW[2048];   // 32 KB
    for (int i = threadIdx.x; i < 2048; i += 256) sW[i] = wfrag[i];
    __syncthreads();
    const int wid = threadIdx.x >> 6, lane = threadIdx.x & 63;
    const int quad = lane >> 4, l16 = lane & 15;
    const int m0 = blockIdx.x * 128 + wid * 32;

    bf16x8 af[2][4];
#pragma unroll
    for (int mt = 0; mt < 2; ++mt) {
        int row = m0 + mt * 16 + l16;
        row = (row < nrows) ? row : (nrows - 1);
        const uint4* hrow = (const uint4*)(hb + (size_t)row * 128);
#pragma unroll
        for (int ks = 0; ks < 4; ++ks)
            af[mt][ks] = __builtin_bit_cast(bf16x8, hrow[ks * 4 + quad]);
    }

    f32x4 acc[2][8];
#pragma unroll
    for (int mt = 0; mt < 2; ++mt)
#pragma unroll
        for (int ct = 0; ct < 8; ++ct) acc[mt][ct] = (f32x4){0.f, 0.f, 0.f, 0.f};

#pragma unroll
    for (int ct = 0; ct < 8; ++ct) {
#pragma unroll
        for (int ks = 0; ks < 4; ++ks) {
            bf16x8 bf = __builtin_bit_cast(bf16x8, sW[(ct * 4 + ks) * 64 + lane]);
            acc[0][ct] = __builtin_amdgcn_mfma_f32_16x16x32_bf16(af[0][ks], bf, acc[0][ct], 0, 0, 0);
            acc[1][ct] = __builtin_amdgcn_mfma_f32_16x16x32_bf16(af[1][ks], bf, acc[1][ct], 0, 0, 0);
        }
    }

#pragma unroll
    for (int mt = 0; mt < 2; ++mt) {
#pragma unroll
        for (int ct = 0; ct < 8; ++ct) {
            int col = ct * 16 + l16;
#pragma unroll
            for (int r = 0; r < 4; ++r) {
                int row = m0 + mt * 16 + quad * 4 + r;
                if (row < nrows) {
                    if (col < 64) {
                        z2[(size_t)row * 64 + col] = f2bf(acc[mt][ct][r]);
                    } else {
                        w2[(size_t)row * 64 + (col - 64)] = acc[mt][ct][r] + bias[col - 64];
                    }
                }
            }
        }
    }
}

extern "C" void kernel_launch(void* const* d_in, const int* in_sizes, int n_in,
                              void* d_out, int out_size, void* d_ws, size_t ws_size,
                              hipStream_t stream) {
    const float* x    = (const float*)d_in[0];
    const float* W1_l = (const float*)d_in[1];
    const float* b1   = (const float*)d_in[2];
    const float* W1_r = (const float*)d_in[3];
    const float* W2_l = (const float*)d_in[4];
    const float* b2   = (const float*)d_in[5];
    const float* W2_r = (const float*)d_in[6];
    const void*  ei   = d_in[7];
    float* out = (float*)d_out;

    const int N = in_sizes[0] / 128;      // 100000
    const int E = in_sizes[7] / 2;        // 1600000
    const int nbuck = (N + 255) >> 8;     // 391

    // workspace layout
    uintptr_t base = (uintptr_t)d_ws;
    int* flag = (int*)base;                                   // 1 int
    int* bucket_cnt  = (int*)(base + 64);                     // nbuck
    int* bucket_base = bucket_cnt + MAXBUCK;                  // nbuck+1
    int* bucket_pos  = bucket_base + MAXBUCK + 1;             // nbuck
    int* off = (int*)(base + 4096 + 3 * MAXBUCK * 4);
    off = (int*)(((uintptr_t)off + 255) & ~(uintptr_t)255);   // N+1
    int* csr = off + (N + 1);                                 // E
    uintptr_t p = ((uintptr_t)(csr + E) + 255) & ~(uintptr_t)255;
    unsigned short* xb    = (unsigned short*)p; p += (size_t)N * 128 * 2;   // bf16 x
    unsigned short* meanb = (unsigned short*)p; p += (size_t)N * 128 * 2;   // bf16 mean / z2 / ebuf
    unsigned short* hb    = (unsigned short*)p; p += (size_t)N * 128 * 2;   // bf16 h
    uint4* w1frag = (uint4*)p; p += 4096 * 16;
    uint4* w2frag = (uint4*)p; p += 2048 * 16;
    uint2* ebuf = (uint2*)meanb;           // dead before agg_mean128_bf writes meanb
    unsigned short* z2 = meanb;            // meanb dead after gemm1
    float* w2 = (float*)xb;                // xb dead after gemm1

    const int* ei32 = (const int*)ei;
    const long long* ei64 = (const long long*)ei;

    detect_zero<<<1, 256, 0, stream>>>(ei, N, flag, bucket_cnt);

    // fused prep: cvt | w1frag | w2frag | coarse hist
    long long n8 = (long long)N * 128 / 8;
    int ncvt = (int)((n8 + 255) / 256);
    prep_kernel<<<ncvt + 16 + 8 + HISTB, 256, 0, stream>>>(
        x, xb, n8, ncvt, W1_l, W1_r, w1frag, W2_l, W2_r, w2frag,
        ei32, ei64, flag, E, nbuck, bucket_cnt);

    bucket_scan<<<1, 256, 0, stream>>>(bucket_cnt, nbuck, bucket_base, bucket_pos);
    int ept = (E + P2B * 256 - 1) / (P2B * 256);   // 13 for E=1.6M (<= MAXEPT)
    pass2_partition<<<P2B, 256, 0, stream>>>(ei32, ei64, flag, E, ept, nbuck,
                                             bucket_pos, ebuf);
    pass3_finalize<<<nbuck, 256, 0, stream>>>(ebuf, bucket_base, nbuck, N, E, off, csr);

    int ablocks = (N + 3) / 4;
    int gblocks = (N + 127) / 128;

    // layer 1
    agg_mean128_bf<<<ablocks, 256, 0, stream>>>(xb, off, csr, meanb, N);
    gemm1_mfma<<<gblocks, 256, 0, stream>>>(meanb, xb, w1frag, b1, hb, N);

    // layer 2 (commuted)
    gemm2_mfma<<<gblocks, 256, 0, stream>>>(hb, w2frag, b2, z2, w2, N);
    agg_mean64_bf_ep<<<ablocks, 256, 0, stream>>>(z2, w2, off, csr, out, N);
}

// Round 8
// 328.787 us; speedup vs baseline: 2.4232x; 1.0074x over previous
//
#include <hip/hip_runtime.h>
#include <hip/hip_bf16.h>
#include <cstdint>

// GraphSAGE 2-layer, bf16 features + fp32 accumulate, MFMA GEMMs.
// Layer1: h   = relu([mean_agg(x) | x] @ [W1_l; W1_r] + b1)   (K=256 MFMA GEMM)
// Layer2: out = mean_agg(h @ W2_l) + h @ W2_r + b2            (agg commutes w/ linear)
// gemm1+gemm2 FUSED (h never hits global; per-wave LDS transpose C->A layout).
// CSR via dst-bucketed partition; ebuf packed 4B/edge (src<<8|dst_local).
// Aggs: 16B/lane gathers, 2 loads deep (R5-proven), f32x2 packed accumulate.
// NOTE: fdot2_f32_bf16 gave WRONG results on gfx950 (R6) — do not use.

typedef __bf16 bf16x8 __attribute__((ext_vector_type(8)));
typedef float f32x4 __attribute__((ext_vector_type(4)));
typedef float f32x2 __attribute__((ext_vector_type(2)));

#define MAXBUCK 400   // >= ceil(100352/256); N=100000 -> 391 buckets
#define MAXEPT 16
#define HISTB 512     // hist blocks inside prep kernel
#define P2B 512       // pass2 blocks
#define HSTRIDE 136   // bf16 elems per h-scratch row (272B, 16B-aligned, bank-skewed)

__device__ __forceinline__ unsigned short f2bf(float f) {
    union { float f; unsigned int u; } v; v.f = f;
    unsigned int u = v.u;
    unsigned int r = ((u >> 16) & 1u) + 0x7fffu;
    return (unsigned short)((u + r) >> 16);
}

// unpack uint (2 bf16) -> f32x2 {lo, hi}
__device__ __forceinline__ f32x2 up2(unsigned int u) {
    uint2 t; t.x = u << 16; t.y = u & 0xffff0000u;
    return __builtin_bit_cast(f32x2, t);
}
__device__ __forceinline__ void accp(const uint4& v, f32x2* a) {
    a[0] += up2(v.x);
    a[1] += up2(v.y);
    a[2] += up2(v.z);
    a[3] += up2(v.w);
}
__device__ __forceinline__ void accpw(const uint4& v, float w, f32x2* a) {
    a[0] += up2(v.x) * w;
    a[1] += up2(v.y) * w;
    a[2] += up2(v.z) * w;
    a[3] += up2(v.w) * w;
}

__device__ __forceinline__ int edge_val(const int* ei32, const long long* ei64,
                                        int is64, size_t idx) {
    return is64 ? (int)ei64[idx] : ei32[idx];
}

// ---------------- detect edge dtype + zero bucket counters ----------------
__global__ __launch_bounds__(256) void detect_zero(const void* ei, int n_nodes,
                                                   int* flag, int* bucket_cnt) {
    for (int i = threadIdx.x; i < MAXBUCK; i += 256) bucket_cnt[i] = 0;
    if (threadIdx.x == 0) {
        const long long* p = (const long long*)ei;
        int ok = 1;
        for (int i = 0; i < 8; ++i) {
            long long v = p[i];
            if (v < 0 || v >= n_nodes) ok = 0;
        }
        *flag = ok;
    }
}

// ---------------- fused prep: cvt x->bf16 | w1 frags | w2 frags | coarse hist
__global__ __launch_bounds__(256) void prep_kernel(const float* __restrict__ x,
                                                   unsigned short* __restrict__ xb,
                                                   long long n8, int ncvt,
                                                   const float* __restrict__ W1l,
                                                   const float* __restrict__ W1r,
                                                   uint4* __restrict__ w1frag,
                                                   const float* __restrict__ W2l,
                                                   const float* __restrict__ W2r,
                                                   uint4* __restrict__ w2frag,
                                                   const int* ei32, const long long* ei64,
                                                   const int* flag, int E, int nbuck,
                                                   int* bucket_cnt) {
    int b = blockIdx.x;
    if (b < ncvt) {
        long long i = (long long)b * 256 + threadIdx.x;
        if (i >= n8) return;
        const float4* p = (const float4*)(x + i * 8);
        float4 a = p[0], c = p[1];
        uint4 o;
        o.x = (unsigned)f2bf(a.x) | ((unsigned)f2bf(a.y) << 16);
        o.y = (unsigned)f2bf(a.z) | ((unsigned)f2bf(a.w) << 16);
        o.z = (unsigned)f2bf(c.x) | ((unsigned)f2bf(c.y) << 16);
        o.w = (unsigned)f2bf(c.z) | ((unsigned)f2bf(c.w) << 16);
        ((uint4*)(xb))[i] = o;
        return;
    }
    if (b < ncvt + 16) {   // W1 frags: Wcat[256][128] = [W1_l; W1_r], 64 frags
        int tid = (b - ncvt) * 256 + threadIdx.x;   // 4096
        int fi = tid >> 6, lane = tid & 63;
        int ct = fi >> 3, ks = fi & 7;
        int k0 = ks * 32 + (lane >> 4) * 8;
        int n = ct * 16 + (lane & 15);
        unsigned short e[8];
#pragma unroll
        for (int j = 0; j < 8; ++j) {
            int k = k0 + j;
            float v = (k < 128) ? W1l[k * 128 + n] : W1r[(k - 128) * 128 + n];
            e[j] = f2bf(v);
        }
        uint4 o;
        o.x = (unsigned)e[0] | ((unsigned)e[1] << 16);
        o.y = (unsigned)e[2] | ((unsigned)e[3] << 16);
        o.z = (unsigned)e[4] | ((unsigned)e[5] << 16);
        o.w = (unsigned)e[6] | ((unsigned)e[7] << 16);
        w1frag[tid] = o;
        return;
    }
    if (b < ncvt + 16 + 8) {  // W2 frags: Wcat2[128][128] = [W2_l | W2_r], 32 frags
        int tid = (b - ncvt - 16) * 256 + threadIdx.x;   // 2048
        int fi = tid >> 6, lane = tid & 63;
        int ct = fi >> 2, ks = fi & 3;
        int k0 = ks * 32 + (lane >> 4) * 8;
        int n = ct * 16 + (lane & 15);
        unsigned short e[8];
#pragma unroll
        for (int j = 0; j < 8; ++j) {
            int k = k0 + j;
            float v = (n < 64) ? W2l[k * 64 + n] : W2r[k * 64 + (n - 64)];
            e[j] = f2bf(v);
        }
        uint4 o;
        o.x = (unsigned)e[0] | ((unsigned)e[1] << 16);
        o.y = (unsigned)e[2] | ((unsigned)e[3] << 16);
        o.z = (unsigned)e[4] | ((unsigned)e[5] << 16);
        o.w = (unsigned)e[6] | ((unsigned)e[7] << 16);
        w2frag[tid] = o;
        return;
    }
    // coarse hist of dst>>8
    __shared__ int lhist[MAXBUCK];
    for (int i = threadIdx.x; i < nbuck; i += 256) lhist[i] = 0;
    __syncthreads();
    int is64 = *flag;
    int hb = b - (ncvt + 24);
    int stride = HISTB * 256;
    for (int e = hb * 256 + threadIdx.x; e < E; e += stride) {
        int d = edge_val(ei32, ei64, is64, (size_t)E + e);
        atomicAdd(&lhist[d >> 8], 1);
    }
    __syncthreads();
    for (int i = threadIdx.x; i < nbuck; i += 256) {
        int c = lhist[i];
        if (c) atomicAdd(&bucket_cnt[i], c);
    }
}

// ---------------- CSR build ----------------
__global__ __launch_bounds__(256) void bucket_scan(const int* bucket_cnt, int nbuck,
                                                   int* bucket_base, int* bucket_pos) {
    int t = threadIdx.x;
    int i0 = 2 * t, i1 = 2 * t + 1;
    int a0 = (i0 < nbuck) ? bucket_cnt[i0] : 0;
    int a1 = (i1 < nbuck) ? bucket_cnt[i1] : 0;
    int tsum = a0 + a1;
    __shared__ int sc[256];
    sc[t] = tsum;
    __syncthreads();
    for (int o = 1; o < 256; o <<= 1) {
        int x = (t >= o) ? sc[t - o] : 0;
        __syncthreads();
        if (t >= o) sc[t] += x;
        __syncthreads();
    }
    int excl = sc[t] - tsum;
    if (i0 <= nbuck) { bucket_base[i0] = excl; if (i0 < nbuck) bucket_pos[i0] = excl; }
    if (i1 <= nbuck) { bucket_base[i1] = excl + a0; if (i1 < nbuck) bucket_pos[i1] = excl + a0; }
    if (t == 255) bucket_base[nbuck] = sc[255];
}

// pass2: partition edges into bucket-ordered packed entries (src<<8 | dst_local)
__global__ __launch_bounds__(256) void pass2_partition(const int* ei32, const long long* ei64,
                                                       const int* flag, int E, int ept,
                                                       int nbuck, int* bucket_pos,
                                                       unsigned* ebuf) {
    __shared__ int lhist[MAXBUCK];
    __shared__ int gbase[MAXBUCK];
    for (int i = threadIdx.x; i < nbuck; i += 256) lhist[i] = 0;
    __syncthreads();
    int is64 = *flag;
    int base_e = blockIdx.x * (ept * 256);
    unsigned ed[MAXEPT];
    int bidx[MAXEPT];
    int slot[MAXEPT];
#pragma unroll 4
    for (int i = 0; i < ept; ++i) {
        int e = base_e + i * 256 + threadIdx.x;
        if (e < E) {
            int s = edge_val(ei32, ei64, is64, (size_t)e);
            int d = edge_val(ei32, ei64, is64, (size_t)E + e);
            ed[i] = ((unsigned)s << 8) | (unsigned)(d & 255);
            bidx[i] = d >> 8;
            slot[i] = atomicAdd(&lhist[d >> 8], 1);
        } else {
            slot[i] = -1;
        }
    }
    __syncthreads();
    for (int i = threadIdx.x; i < nbuck; i += 256) {
        int c = lhist[i];
        gbase[i] = c ? atomicAdd(&bucket_pos[i], c) : 0;
    }
    __syncthreads();
#pragma unroll 4
    for (int i = 0; i < ept; ++i) {
        if (slot[i] >= 0) {
            ebuf[gbase[bidx[i]] + slot[i]] = ed[i];
        }
    }
}

__global__ __launch_bounds__(256) void pass3_finalize(const unsigned* __restrict__ ebuf,
                                                      const int* __restrict__ bucket_base,
                                                      int nbuck, int N, int E,
                                                      int* __restrict__ off,
                                                      int* __restrict__ csr) {
    __shared__ int lcnt[256];
    __shared__ int lexcl[256];
    __shared__ int sc[256];
    int b = blockIdx.x;
    int t = threadIdx.x;
    int d0 = b << 8;
    int nb = N - d0; if (nb > 256) nb = 256;
    int base = bucket_base[b];
    int m = bucket_base[b + 1] - base;

    lcnt[t] = 0;
    __syncthreads();
    for (int j = t; j < m; j += 256) {
        int li = (int)(ebuf[base + j] & 255u);
        atomicAdd(&lcnt[li], 1);
    }
    __syncthreads();
    int v = lcnt[t];
    sc[t] = v;
    __syncthreads();
    for (int o = 1; o < 256; o <<= 1) {
        int x = (t >= o) ? sc[t - o] : 0;
        __syncthreads();
        if (t >= o) sc[t] += x;
        __syncthreads();
    }
    int excl = sc[t] - v;
    lexcl[t] = excl;
    if (t < nb) off[d0 + t] = base + excl;
    if (b == nbuck - 1 && t == 0) off[N] = E;
    lcnt[t] = 0;   // reuse as running pos
    __syncthreads();
    for (int j = t; j < m; j += 256) {
        unsigned ed = ebuf[base + j];
        int li = (int)(ed & 255u);
        int slot = atomicAdd(&lcnt[li], 1);
        csr[base + lexcl[li] + slot] = (int)(ed >> 8);
    }
}

// ---------------- mean aggregation, D=128 bf16, 16B/lane ----------------
// one wave per node; l16 = uint4 slot (8 dims), quad = edge within group of 4.
// main loop: 8 edges / iter, 2 independent 1KB loads (R5-proven depth).
__global__ __launch_bounds__(256) void agg_mean128_bf(const unsigned short* __restrict__ Xb,
                                                      const int* __restrict__ off,
                                                      const int* __restrict__ csr,
                                                      unsigned short* __restrict__ outb,
                                                      int n_nodes) {
    int node = blockIdx.x * 4 + (threadIdx.x >> 6);
    if (node >= n_nodes) return;
    int lane = threadIdx.x & 63;
    int quad = lane >> 4;
    int l16 = lane & 15;
    int s0 = off[node], s1 = off[node + 1];
    int deg = s1 - s0;
    f32x2 A0[4], A1[4];
#pragma unroll
    for (int k = 0; k < 4; ++k) { A0[k] = (f32x2){0.f, 0.f}; A1[k] = (f32x2){0.f, 0.f}; }
    int j = s0;
    for (; j + 8 <= s1; j += 8) {
        int p0 = csr[j + quad];
        int p1 = csr[j + 4 + quad];
        uint4 v0 = ((const uint4*)(Xb + (size_t)p0 * 128))[l16];
        uint4 v1 = ((const uint4*)(Xb + (size_t)p1 * 128))[l16];
        accp(v0, A0);
        accp(v1, A1);
    }
    if (j + 4 <= s1) {
        int p = csr[j + quad];
        uint4 v = ((const uint4*)(Xb + (size_t)p * 128))[l16];
        accp(v, A0);
        j += 4;
    }
    if (j < s1) {  // masked tail, 1..3 edges
        int jj = j + quad;
        int p = csr[(jj < s1) ? jj : (s1 - 1)];
        float w = (jj < s1) ? 1.0f : 0.0f;
        uint4 v = ((const uint4*)(Xb + (size_t)p * 128))[l16];
        accpw(v, w, A1);
    }
    float r[8];
#pragma unroll
    for (int k = 0; k < 4; ++k) {
        f32x2 s = A0[k] + A1[k];
        r[2 * k] = s.x;
        r[2 * k + 1] = s.y;
    }
#pragma unroll
    for (int k = 0; k < 8; ++k) r[k] += __shfl(r[k], lane ^ 16);
#pragma unroll
    for (int k = 0; k < 8; ++k) r[k] += __shfl(r[k], lane ^ 32);
    float inv = (deg > 0) ? 1.0f / (float)deg : 0.0f;
    if (quad == 0) {
        uint4 o;
        o.x = (unsigned)f2bf(r[0] * inv) | ((unsigned)f2bf(r[1] * inv) << 16);
        o.y = (unsigned)f2bf(r[2] * inv) | ((unsigned)f2bf(r[3] * inv) << 16);
        o.z = (unsigned)f2bf(r[4] * inv) | ((unsigned)f2bf(r[5] * inv) << 16);
        o.w = (unsigned)f2bf(r[6] * inv) | ((unsigned)f2bf(r[7] * inv) << 16);
        ((uint4*)(outb + (size_t)node * 128))[l16] = o;
    }
}

// ---------------- mean aggregation, D=64 bf16, 16B/lane, epilogue +w2 -------
__global__ __launch_bounds__(256) void agg_mean64_bf_ep(const unsigned short* __restrict__ Zb,
                                                        const float* __restrict__ Wadd,
                                                        const int* __restrict__ off,
                                                        const int* __restrict__ csr,
                                                        float* __restrict__ out,
                                                        int n_nodes) {
    int node = blockIdx.x * 4 + (threadIdx.x >> 6);
    if (node >= n_nodes) return;
    int lane = threadIdx.x & 63;
    int oct = lane >> 3;
    int l8 = lane & 7;
    int s0 = off[node], s1 = off[node + 1];
    int deg = s1 - s0;
    f32x2 A0[4], A1[4];
#pragma unroll
    for (int k = 0; k < 4; ++k) { A0[k] = (f32x2){0.f, 0.f}; A1[k] = (f32x2){0.f, 0.f}; }
    int j = s0;
    for (; j + 16 <= s1; j += 16) {
        int p0 = csr[j + oct];
        int p1 = csr[j + 8 + oct];
        uint4 v0 = ((const uint4*)(Zb + (size_t)p0 * 64))[l8];
        uint4 v1 = ((const uint4*)(Zb + (size_t)p1 * 64))[l8];
        accp(v0, A0);
        accp(v1, A1);
    }
    if (j + 8 <= s1) {
        int p = csr[j + oct];
        uint4 v = ((const uint4*)(Zb + (size_t)p * 64))[l8];
        accp(v, A0);
        j += 8;
    }
    if (j < s1) {  // masked tail, 1..7 edges
        int jj = j + oct;
        int p = csr[(jj < s1) ? jj : (s1 - 1)];
        float w = (jj < s1) ? 1.0f : 0.0f;
        uint4 v = ((const uint4*)(Zb + (size_t)p * 64))[l8];
        accpw(v, w, A1);
    }
    float r[8];
#pragma unroll
    for (int k = 0; k < 4; ++k) {
        f32x2 s = A0[k] + A1[k];
        r[2 * k] = s.x;
        r[2 * k + 1] = s.y;
    }
#pragma unroll
    for (int k = 0; k < 8; ++k) r[k] += __shfl(r[k], lane ^ 8);
#pragma unroll
    for (int k = 0; k < 8; ++k) r[k] += __shfl(r[k], lane ^ 16);
#pragma unroll
    for (int k = 0; k < 8; ++k) r[k] += __shfl(r[k], lane ^ 32);
    float inv = (deg > 0) ? 1.0f / (float)deg : 0.0f;
    if (oct == 0) {
        const float4* wp = (const float4*)(Wadd + (size_t)node * 64 + l8 * 8);
        float4 w0 = wp[0], w1 = wp[1];
        float4 o0, o1;
        o0.x = r[0] * inv + w0.x; o0.y = r[1] * inv + w0.y;
        o0.z = r[2] * inv + w0.z; o0.w = r[3] * inv + w0.w;
        o1.x = r[4] * inv + w1.x; o1.y = r[5] * inv + w1.y;
        o1.z = r[6] * inv + w1.z; o1.w = r[7] * inv + w1.w;
        float4* op = (float4*)(out + (size_t)node * 64 + l8 * 8);
        op[0] = o0; op[1] = o1;
    }
}

// ---------------- FUSED GEMM1+GEMM2 (MFMA) ----------------
// per 128-row block: h = relu([mean|x] @ W1cat + b1) (K=256), then per-wave
// LDS transpose of the h m-tile (C-layout -> A-layout) and
// z2 = h@W2_l (bf16), w2 = h@W2_r + b2 (fp32)  (K=128, N=128 concat).
__global__ __launch_bounds__(256, 1) void gemm12_mfma(const unsigned short* __restrict__ meanb,
                                                      const unsigned short* __restrict__ xb,
                                                      const uint4* __restrict__ w1frag,
                                                      const uint4* __restrict__ w2frag,
                                                      const float* __restrict__ b1,
                                                      const float* __restrict__ b2,
                                                      unsigned short* __restrict__ z2,
                                                      float* __restrict__ w2out,
                                                      int nrows) {
    __shared__ uint4 sW1[4096];                   // 64 KB
    __shared__ uint4 sW2[2048];                   // 32 KB
    __shared__ unsigned short hs[4][16 * HSTRIDE]; // 4 x 4352 B
    for (int i = threadIdx.x; i < 4096; i += 256) sW1[i] = w1frag[i];
    for (int i = threadIdx.x; i < 2048; i += 256) sW2[i] = w2frag[i];
    __syncthreads();
    const int wid = threadIdx.x >> 6, lane = threadIdx.x & 63;
    const int quad = lane >> 4, l16 = lane & 15;
    const int m0 = blockIdx.x * 128 + wid * 32;
    unsigned short* hsw = &hs[wid][0];

#pragma unroll
    for (int mt = 0; mt < 2; ++mt) {
        int row = m0 + mt * 16 + l16;
        int rowc = (row < nrows) ? row : (nrows - 1);
        const uint4* mrow = (const uint4*)(meanb + (size_t)rowc * 128);
        const uint4* xrow = (const uint4*)(xb + (size_t)rowc * 128);
        bf16x8 af[8];
#pragma unroll
        for (int ks = 0; ks < 4; ++ks) {
            af[ks]     = __builtin_bit_cast(bf16x8, mrow[ks * 4 + quad]);
            af[ks + 4] = __builtin_bit_cast(bf16x8, xrow[ks * 4 + quad]);
        }

        // ---- gemm1 for this m-tile ----
#pragma unroll
        for (int ct = 0; ct < 8; ++ct) {
            f32x4 acc = (f32x4){0.f, 0.f, 0.f, 0.f};
#pragma unroll
            for (int ks = 0; ks < 8; ++ks) {
                bf16x8 bf = __builtin_bit_cast(bf16x8, sW1[(ct * 8 + ks) * 64 + lane]);
                acc = __builtin_amdgcn_mfma_f32_16x16x32_bf16(af[ks], bf, acc, 0, 0, 0);
            }
            // epilogue: bias + relu -> bf16 into per-wave LDS scratch (C-layout)
            int col = ct * 16 + l16;
            float bb = b1[col];
#pragma unroll
            for (int r = 0; r < 4; ++r) {
                float v = fmaxf(acc[r] + bb, 0.f);
                hs[wid][(quad * 4 + r) * HSTRIDE + col] = f2bf(v);
            }
        }

        // ---- transpose read: A-frags of h (row = l16, k = ks*32 + quad*8 + j)
        bf16x8 af2[4];
#pragma unroll
        for (int ks = 0; ks < 4; ++ks) {
            uint4 t = *(const uint4*)(hsw + l16 * HSTRIDE + ks * 32 + quad * 8);
            af2[ks] = __builtin_bit_cast(bf16x8, t);
        }

        // ---- gemm2 for this m-tile ----
#pragma unroll
        for (int ct = 0; ct < 8; ++ct) {
            f32x4 acc = (f32x4){0.f, 0.f, 0.f, 0.f};
#pragma unroll
            for (int ks = 0; ks < 4; ++ks) {
                bf16x8 bf = __builtin_bit_cast(bf16x8, sW2[(ct * 4 + ks) * 64 + lane]);
                acc = __builtin_amdgcn_mfma_f32_16x16x32_bf16(af2[ks], bf, acc, 0, 0, 0);
            }
            int col = ct * 16 + l16;
#pragma unroll
            for (int r = 0; r < 4; ++r) {
                int orow = m0 + mt * 16 + quad * 4 + r;
                if (orow < nrows) {
                    if (col < 64) {
                        z2[(size_t)orow * 64 + col] = f2bf(acc[r]);
                    } else {
                        w2out[(size_t)orow * 64 + (col - 64)] = acc[r] + b2[col - 64];
                    }
                }
            }
        }
    }
}

extern "C" void kernel_launch(void* const* d_in, const int* in_sizes, int n_in,
                              void* d_out, int out_size, void* d_ws, size_t ws_size,
                              hipStream_t stream) {
    const float* x    = (const float*)d_in[0];
    const float* W1_l = (const float*)d_in[1];
    const float* b1   = (const float*)d_in[2];
    const float* W1_r = (const float*)d_in[3];
    const float* W2_l = (const float*)d_in[4];
    const float* b2   = (const float*)d_in[5];
    const float* W2_r = (const float*)d_in[6];
    const void*  ei   = d_in[7];
    float* out = (float*)d_out;

    const int N = in_sizes[0] / 128;      // 100000
    const int E = in_sizes[7] / 2;        // 1600000
    const int nbuck = (N + 255) >> 8;     // 391

    // workspace layout
    uintptr_t base = (uintptr_t)d_ws;
    int* flag = (int*)base;                                   // 1 int
    int* bucket_cnt  = (int*)(base + 64);                     // nbuck
    int* bucket_base = bucket_cnt + MAXBUCK;                  // nbuck+1
    int* bucket_pos  = bucket_base + MAXBUCK + 1;             // nbuck
    int* off = (int*)(base + 4096 + 3 * MAXBUCK * 4);
    off = (int*)(((uintptr_t)off + 255) & ~(uintptr_t)255);   // N+1
    int* csr = off + (N + 1);                                 // E
    uintptr_t p = ((uintptr_t)(csr + E) + 255) & ~(uintptr_t)255;
    unsigned short* xb    = (unsigned short*)p; p += (size_t)N * 128 * 2;   // bf16 x (later w2 fp32, same extent)
    unsigned short* meanb = (unsigned short*)p; p += (size_t)N * 128 * 2;   // ebuf / bf16 mean
    unsigned short* hbr   = (unsigned short*)p; p += (size_t)N * 128 * 2;   // z2 region
    uint4* w1frag = (uint4*)p; p += 4096 * 16;
    uint4* w2frag = (uint4*)p; p += 2048 * 16;
    unsigned* ebuf = (unsigned*)meanb;     // dead before agg_mean128_bf writes meanb
    unsigned short* z2 = hbr;              // bf16 N*64
    float* w2 = (float*)xb;                // fp32 N*64; xb dead after gemm12 reads it
                                           // (block-disjoint rows, read-before-write)

    const int* ei32 = (const int*)ei;
    const long long* ei64 = (const long long*)ei;

    detect_zero<<<1, 256, 0, stream>>>(ei, N, flag, bucket_cnt);

    // fused prep: cvt | w1frag | w2frag | coarse hist
    long long n8 = (long long)N * 128 / 8;
    int ncvt = (int)((n8 + 255) / 256);
    prep_kernel<<<ncvt + 16 + 8 + HISTB, 256, 0, stream>>>(
        x, xb, n8, ncvt, W1_l, W1_r, w1frag, W2_l, W2_r, w2frag,
        ei32, ei64, flag, E, nbuck, bucket_cnt);

    bucket_scan<<<1, 256, 0, stream>>>(bucket_cnt, nbuck, bucket_base, bucket_pos);
    int ept = (E + P2B * 256 - 1) / (P2B * 256);   // 13 for E=1.6M (<= MAXEPT)
    pass2_partition<<<P2B, 256, 0, stream>>>(ei32, ei64, flag, E, ept, nbuck,
                                             bucket_pos, ebuf);
    pass3_finalize<<<nbuck, 256, 0, stream>>>(ebuf, bucket_base, nbuck, N, E, off, csr);

    int ablocks = (N + 3) / 4;
    int gblocks = (N + 127) / 128;

    // layer 1 agg
    agg_mean128_bf<<<ablocks, 256, 0, stream>>>(xb, off, csr, meanb, N);
    // fused layer-1 linear + layer-2 linear (h stays on-chip)
    gemm12_mfma<<<gblocks, 256, 0, stream>>>(meanb, xb, w1frag, w2frag, b1, b2,
                                             z2, w2, N);
    // layer 2 agg (commuted) + epilogue
    agg_mean64_bf_ep<<<ablocks, 256, 0, stream>>>(z2, w2, off, csr, out, N);
}

// Round 9
// 319.198 us; speedup vs baseline: 2.4960x; 1.0300x over previous
//
#include <hip/hip_runtime.h>
#include <hip/hip_bf16.h>
#include <cstdint>

// GraphSAGE 2-layer, bf16 features + fp32 accumulate, MFMA GEMMs.
// Layer1: h   = relu([mean_agg(x) | x] @ [W1_l; W1_r] + b1)   (K=256 MFMA GEMM)
// Layer2: out = mean_agg(h @ W2_l) + h @ W2_r + b2            (agg commutes w/ linear)
// gemm1+gemm2 FUSED; W2 staged in LDS, W1 frags streamed from global (L1/L2),
// h round-trips per-wave LDS scratch (C->A layout). LDS 49.4KB -> 3 blocks/CU.
// CSR via dst-bucketed partition; ebuf packed 4B/edge (src<<8|dst_local).
// Aggs: 16B/lane gathers, 2 loads deep (R5-proven), f32x2 packed accumulate.
// NOTE: fdot2_f32_bf16 gave WRONG results on gfx950 (R6) — do not use.
// NOTE: R8 staged W1+W2 in LDS (113KB) -> 1 block/CU, 66us latency-bound. Don't.

typedef __bf16 bf16x8 __attribute__((ext_vector_type(8)));
typedef float f32x4 __attribute__((ext_vector_type(4)));
typedef float f32x2 __attribute__((ext_vector_type(2)));

#define MAXBUCK 400   // >= ceil(100352/256); N=100000 -> 391 buckets
#define MAXEPT 16
#define HISTB 512     // hist blocks inside prep kernel
#define P2B 512       // pass2 blocks
#define HSTRIDE 136   // bf16 elems per h-scratch row (272B, 16B-aligned)

__device__ __forceinline__ unsigned short f2bf(float f) {
    union { float f; unsigned int u; } v; v.f = f;
    unsigned int u = v.u;
    unsigned int r = ((u >> 16) & 1u) + 0x7fffu;
    return (unsigned short)((u + r) >> 16);
}

// unpack uint (2 bf16) -> f32x2 {lo, hi}
__device__ __forceinline__ f32x2 up2(unsigned int u) {
    uint2 t; t.x = u << 16; t.y = u & 0xffff0000u;
    return __builtin_bit_cast(f32x2, t);
}
__device__ __forceinline__ void accp(const uint4& v, f32x2* a) {
    a[0] += up2(v.x);
    a[1] += up2(v.y);
    a[2] += up2(v.z);
    a[3] += up2(v.w);
}
__device__ __forceinline__ void accpw(const uint4& v, float w, f32x2* a) {
    a[0] += up2(v.x) * w;
    a[1] += up2(v.y) * w;
    a[2] += up2(v.z) * w;
    a[3] += up2(v.w) * w;
}

__device__ __forceinline__ int edge_val(const int* ei32, const long long* ei64,
                                        int is64, size_t idx) {
    return is64 ? (int)ei64[idx] : ei32[idx];
}

// ---------------- detect edge dtype + zero bucket counters ----------------
__global__ __launch_bounds__(256) void detect_zero(const void* ei, int n_nodes,
                                                   int* flag, int* bucket_cnt) {
    for (int i = threadIdx.x; i < MAXBUCK; i += 256) bucket_cnt[i] = 0;
    if (threadIdx.x == 0) {
        const long long* p = (const long long*)ei;
        int ok = 1;
        for (int i = 0; i < 8; ++i) {
            long long v = p[i];
            if (v < 0 || v >= n_nodes) ok = 0;
        }
        *flag = ok;
    }
}

// ---------------- fused prep: cvt x->bf16 | w1 frags | w2 frags | coarse hist
__global__ __launch_bounds__(256) void prep_kernel(const float* __restrict__ x,
                                                   unsigned short* __restrict__ xb,
                                                   long long n8, int ncvt,
                                                   const float* __restrict__ W1l,
                                                   const float* __restrict__ W1r,
                                                   uint4* __restrict__ w1frag,
                                                   const float* __restrict__ W2l,
                                                   const float* __restrict__ W2r,
                                                   uint4* __restrict__ w2frag,
                                                   const int* ei32, const long long* ei64,
                                                   const int* flag, int E, int nbuck,
                                                   int* bucket_cnt) {
    int b = blockIdx.x;
    if (b < ncvt) {
        long long i = (long long)b * 256 + threadIdx.x;
        if (i >= n8) return;
        const float4* p = (const float4*)(x + i * 8);
        float4 a = p[0], c = p[1];
        uint4 o;
        o.x = (unsigned)f2bf(a.x) | ((unsigned)f2bf(a.y) << 16);
        o.y = (unsigned)f2bf(a.z) | ((unsigned)f2bf(a.w) << 16);
        o.z = (unsigned)f2bf(c.x) | ((unsigned)f2bf(c.y) << 16);
        o.w = (unsigned)f2bf(c.z) | ((unsigned)f2bf(c.w) << 16);
        ((uint4*)(xb))[i] = o;
        return;
    }
    if (b < ncvt + 16) {   // W1 frags: Wcat[256][128] = [W1_l; W1_r], 64 frags
        int tid = (b - ncvt) * 256 + threadIdx.x;   // 4096
        int fi = tid >> 6, lane = tid & 63;
        int ct = fi >> 3, ks = fi & 7;
        int k0 = ks * 32 + (lane >> 4) * 8;
        int n = ct * 16 + (lane & 15);
        unsigned short e[8];
#pragma unroll
        for (int j = 0; j < 8; ++j) {
            int k = k0 + j;
            float v = (k < 128) ? W1l[k * 128 + n] : W1r[(k - 128) * 128 + n];
            e[j] = f2bf(v);
        }
        uint4 o;
        o.x = (unsigned)e[0] | ((unsigned)e[1] << 16);
        o.y = (unsigned)e[2] | ((unsigned)e[3] << 16);
        o.z = (unsigned)e[4] | ((unsigned)e[5] << 16);
        o.w = (unsigned)e[6] | ((unsigned)e[7] << 16);
        w1frag[tid] = o;
        return;
    }
    if (b < ncvt + 16 + 8) {  // W2 frags: Wcat2[128][128] = [W2_l | W2_r], 32 frags
        int tid = (b - ncvt - 16) * 256 + threadIdx.x;   // 2048
        int fi = tid >> 6, lane = tid & 63;
        int ct = fi >> 2, ks = fi & 3;
        int k0 = ks * 32 + (lane >> 4) * 8;
        int n = ct * 16 + (lane & 15);
        unsigned short e[8];
#pragma unroll
        for (int j = 0; j < 8; ++j) {
            int k = k0 + j;
            float v = (n < 64) ? W2l[k * 64 + n] : W2r[k * 64 + (n - 64)];
            e[j] = f2bf(v);
        }
        uint4 o;
        o.x = (unsigned)e[0] | ((unsigned)e[1] << 16);
        o.y = (unsigned)e[2] | ((unsigned)e[3] << 16);
        o.z = (unsigned)e[4] | ((unsigned)e[5] << 16);
        o.w = (unsigned)e[6] | ((unsigned)e[7] << 16);
        w2frag[tid] = o;
        return;
    }
    // coarse hist of dst>>8
    __shared__ int lhist[MAXBUCK];
    for (int i = threadIdx.x; i < nbuck; i += 256) lhist[i] = 0;
    __syncthreads();
    int is64 = *flag;
    int hb = b - (ncvt + 24);
    int stride = HISTB * 256;
    for (int e = hb * 256 + threadIdx.x; e < E; e += stride) {
        int d = edge_val(ei32, ei64, is64, (size_t)E + e);
        atomicAdd(&lhist[d >> 8], 1);
    }
    __syncthreads();
    for (int i = threadIdx.x; i < nbuck; i += 256) {
        int c = lhist[i];
        if (c) atomicAdd(&bucket_cnt[i], c);
    }
}

// ---------------- CSR build ----------------
__global__ __launch_bounds__(256) void bucket_scan(const int* bucket_cnt, int nbuck,
                                                   int* bucket_base, int* bucket_pos) {
    int t = threadIdx.x;
    int i0 = 2 * t, i1 = 2 * t + 1;
    int a0 = (i0 < nbuck) ? bucket_cnt[i0] : 0;
    int a1 = (i1 < nbuck) ? bucket_cnt[i1] : 0;
    int tsum = a0 + a1;
    __shared__ int sc[256];
    sc[t] = tsum;
    __syncthreads();
    for (int o = 1; o < 256; o <<= 1) {
        int x = (t >= o) ? sc[t - o] : 0;
        __syncthreads();
        if (t >= o) sc[t] += x;
        __syncthreads();
    }
    int excl = sc[t] - tsum;
    if (i0 <= nbuck) { bucket_base[i0] = excl; if (i0 < nbuck) bucket_pos[i0] = excl; }
    if (i1 <= nbuck) { bucket_base[i1] = excl + a0; if (i1 < nbuck) bucket_pos[i1] = excl + a0; }
    if (t == 255) bucket_base[nbuck] = sc[255];
}

// pass2: partition edges into bucket-ordered packed entries (src<<8 | dst_local)
__global__ __launch_bounds__(256) void pass2_partition(const int* ei32, const long long* ei64,
                                                       const int* flag, int E, int ept,
                                                       int nbuck, int* bucket_pos,
                                                       unsigned* ebuf) {
    __shared__ int lhist[MAXBUCK];
    __shared__ int gbase[MAXBUCK];
    for (int i = threadIdx.x; i < nbuck; i += 256) lhist[i] = 0;
    __syncthreads();
    int is64 = *flag;
    int base_e = blockIdx.x * (ept * 256);
    unsigned ed[MAXEPT];
    int bidx[MAXEPT];
    int slot[MAXEPT];
#pragma unroll 4
    for (int i = 0; i < ept; ++i) {
        int e = base_e + i * 256 + threadIdx.x;
        if (e < E) {
            int s = edge_val(ei32, ei64, is64, (size_t)e);
            int d = edge_val(ei32, ei64, is64, (size_t)E + e);
            ed[i] = ((unsigned)s << 8) | (unsigned)(d & 255);
            bidx[i] = d >> 8;
            slot[i] = atomicAdd(&lhist[d >> 8], 1);
        } else {
            slot[i] = -1;
        }
    }
    __syncthreads();
    for (int i = threadIdx.x; i < nbuck; i += 256) {
        int c = lhist[i];
        gbase[i] = c ? atomicAdd(&bucket_pos[i], c) : 0;
    }
    __syncthreads();
#pragma unroll 4
    for (int i = 0; i < ept; ++i) {
        if (slot[i] >= 0) {
            ebuf[gbase[bidx[i]] + slot[i]] = ed[i];
        }
    }
}

__global__ __launch_bounds__(256) void pass3_finalize(const unsigned* __restrict__ ebuf,
                                                      const int* __restrict__ bucket_base,
                                                      int nbuck, int N, int E,
                                                      int* __restrict__ off,
                                                      int* __restrict__ csr) {
    __shared__ int lcnt[256];
    __shared__ int lexcl[256];
    __shared__ int sc[256];
    int b = blockIdx.x;
    int t = threadIdx.x;
    int d0 = b << 8;
    int nb = N - d0; if (nb > 256) nb = 256;
    int base = bucket_base[b];
    int m = bucket_base[b + 1] - base;

    lcnt[t] = 0;
    __syncthreads();
    for (int j = t; j < m; j += 256) {
        int li = (int)(ebuf[base + j] & 255u);
        atomicAdd(&lcnt[li], 1);
    }
    __syncthreads();
    int v = lcnt[t];
    sc[t] = v;
    __syncthreads();
    for (int o = 1; o < 256; o <<= 1) {
        int x = (t >= o) ? sc[t - o] : 0;
        __syncthreads();
        if (t >= o) sc[t] += x;
        __syncthreads();
    }
    int excl = sc[t] - v;
    lexcl[t] = excl;
    if (t < nb) off[d0 + t] = base + excl;
    if (b == nbuck - 1 && t == 0) off[N] = E;
    lcnt[t] = 0;   // reuse as running pos
    __syncthreads();
    for (int j = t; j < m; j += 256) {
        unsigned ed = ebuf[base + j];
        int li = (int)(ed & 255u);
        int slot = atomicAdd(&lcnt[li], 1);
        csr[base + lexcl[li] + slot] = (int)(ed >> 8);
    }
}

// ---------------- mean aggregation, D=128 bf16, 16B/lane ----------------
__global__ __launch_bounds__(256) void agg_mean128_bf(const unsigned short* __restrict__ Xb,
                                                      const int* __restrict__ off,
                                                      const int* __restrict__ csr,
                                                      unsigned short* __restrict__ outb,
                                                      int n_nodes) {
    int node = blockIdx.x * 4 + (threadIdx.x >> 6);
    if (node >= n_nodes) return;
    int lane = threadIdx.x & 63;
    int quad = lane >> 4;
    int l16 = lane & 15;
    int s0 = off[node], s1 = off[node + 1];
    int deg = s1 - s0;
    f32x2 A0[4], A1[4];
#pragma unroll
    for (int k = 0; k < 4; ++k) { A0[k] = (f32x2){0.f, 0.f}; A1[k] = (f32x2){0.f, 0.f}; }
    int j = s0;
    for (; j + 8 <= s1; j += 8) {
        int p0 = csr[j + quad];
        int p1 = csr[j + 4 + quad];
        uint4 v0 = ((const uint4*)(Xb + (size_t)p0 * 128))[l16];
        uint4 v1 = ((const uint4*)(Xb + (size_t)p1 * 128))[l16];
        accp(v0, A0);
        accp(v1, A1);
    }
    if (j + 4 <= s1) {
        int p = csr[j + quad];
        uint4 v = ((const uint4*)(Xb + (size_t)p * 128))[l16];
        accp(v, A0);
        j += 4;
    }
    if (j < s1) {  // masked tail, 1..3 edges
        int jj = j + quad;
        int p = csr[(jj < s1) ? jj : (s1 - 1)];
        float w = (jj < s1) ? 1.0f : 0.0f;
        uint4 v = ((const uint4*)(Xb + (size_t)p * 128))[l16];
        accpw(v, w, A1);
    }
    float r[8];
#pragma unroll
    for (int k = 0; k < 4; ++k) {
        f32x2 s = A0[k] + A1[k];
        r[2 * k] = s.x;
        r[2 * k + 1] = s.y;
    }
#pragma unroll
    for (int k = 0; k < 8; ++k) r[k] += __shfl(r[k], lane ^ 16);
#pragma unroll
    for (int k = 0; k < 8; ++k) r[k] += __shfl(r[k], lane ^ 32);
    float inv = (deg > 0) ? 1.0f / (float)deg : 0.0f;
    if (quad == 0) {
        uint4 o;
        o.x = (unsigned)f2bf(r[0] * inv) | ((unsigned)f2bf(r[1] * inv) << 16);
        o.y = (unsigned)f2bf(r[2] * inv) | ((unsigned)f2bf(r[3] * inv) << 16);
        o.z = (unsigned)f2bf(r[4] * inv) | ((unsigned)f2bf(r[5] * inv) << 16);
        o.w = (unsigned)f2bf(r[6] * inv) | ((unsigned)f2bf(r[7] * inv) << 16);
        ((uint4*)(outb + (size_t)node * 128))[l16] = o;
    }
}

// ---------------- mean aggregation, D=64 bf16, 16B/lane, epilogue +w2 -------
__global__ __launch_bounds__(256) void agg_mean64_bf_ep(const unsigned short* __restrict__ Zb,
                                                        const float* __restrict__ Wadd,
                                                        const int* __restrict__ off,
                                                        const int* __restrict__ csr,
                                                        float* __restrict__ out,
                                                        int n_nodes) {
    int node = blockIdx.x * 4 + (threadIdx.x >> 6);
    if (node >= n_nodes) return;
    int lane = threadIdx.x & 63;
    int oct = lane >> 3;
    int l8 = lane & 7;
    int s0 = off[node], s1 = off[node + 1];
    int deg = s1 - s0;
    f32x2 A0[4], A1[4];
#pragma unroll
    for (int k = 0; k < 4; ++k) { A0[k] = (f32x2){0.f, 0.f}; A1[k] = (f32x2){0.f, 0.f}; }
    int j = s0;
    for (; j + 16 <= s1; j += 16) {
        int p0 = csr[j + oct];
        int p1 = csr[j + 8 + oct];
        uint4 v0 = ((const uint4*)(Zb + (size_t)p0 * 64))[l8];
        uint4 v1 = ((const uint4*)(Zb + (size_t)p1 * 64))[l8];
        accp(v0, A0);
        accp(v1, A1);
    }
    if (j + 8 <= s1) {
        int p = csr[j + oct];
        uint4 v = ((const uint4*)(Zb + (size_t)p * 64))[l8];
        accp(v, A0);
        j += 8;
    }
    if (j < s1) {  // masked tail, 1..7 edges
        int jj = j + oct;
        int p = csr[(jj < s1) ? jj : (s1 - 1)];
        float w = (jj < s1) ? 1.0f : 0.0f;
        uint4 v = ((const uint4*)(Zb + (size_t)p * 64))[l8];
        accpw(v, w, A1);
    }
    float r[8];
#pragma unroll
    for (int k = 0; k < 4; ++k) {
        f32x2 s = A0[k] + A1[k];
        r[2 * k] = s.x;
        r[2 * k + 1] = s.y;
    }
#pragma unroll
    for (int k = 0; k < 8; ++k) r[k] += __shfl(r[k], lane ^ 8);
#pragma unroll
    for (int k = 0; k < 8; ++k) r[k] += __shfl(r[k], lane ^ 16);
#pragma unroll
    for (int k = 0; k < 8; ++k) r[k] += __shfl(r[k], lane ^ 32);
    float inv = (deg > 0) ? 1.0f / (float)deg : 0.0f;
    if (oct == 0) {
        const float4* wp = (const float4*)(Wadd + (size_t)node * 64 + l8 * 8);
        float4 w0 = wp[0], w1 = wp[1];
        float4 o0, o1;
        o0.x = r[0] * inv + w0.x; o0.y = r[1] * inv + w0.y;
        o0.z = r[2] * inv + w0.z; o0.w = r[3] * inv + w0.w;
        o1.x = r[4] * inv + w1.x; o1.y = r[5] * inv + w1.y;
        o1.z = r[6] * inv + w1.z; o1.w = r[7] * inv + w1.w;
        float4* op = (float4*)(out + (size_t)node * 64 + l8 * 8);
        op[0] = o0; op[1] = o1;
    }
}

// ---------------- FUSED GEMM1+GEMM2 (MFMA), occupancy-fixed ----------------
// per 128-row block: h = relu([mean|x] @ W1cat + b1) (K=256), per-wave LDS
// transpose (C-layout -> A-layout), then z2 = h@W2_l, w2 = h@W2_r + b2.
// W2 staged in LDS (32KB, reused 2x/wave); W1 frags streamed from global
// (coalesced 1KB/load, L1-shared across the block's 4 waves).
// LDS = 32KB + 17KB = 49.4KB -> 3 blocks/CU; VGPR ~130 -> 12 waves/CU.
__global__ __launch_bounds__(256, 3) void gemm12_mfma(const unsigned short* __restrict__ meanb,
                                                      const unsigned short* __restrict__ xb,
                                                      const uint4* __restrict__ w1frag,
                                                      const uint4* __restrict__ w2frag,
                                                      const float* __restrict__ b1,
                                                      const float* __restrict__ b2,
                                                      unsigned short* __restrict__ z2,
                                                      float* __restrict__ w2out,
                                                      int nrows) {
    __shared__ uint4 sW2[2048];                    // 32 KB
    __shared__ unsigned short hs[4][16 * HSTRIDE]; // 4 x 4352 B
    for (int i = threadIdx.x; i < 2048; i += 256) sW2[i] = w2frag[i];
    __syncthreads();
    const int wid = threadIdx.x >> 6, lane = threadIdx.x & 63;
    const int quad = lane >> 4, l16 = lane & 15;
    const int m0 = blockIdx.x * 128 + wid * 32;
    unsigned short* hsw = &hs[wid][0];
    const uint4* w1p = w1frag + lane;

#pragma unroll
    for (int mt = 0; mt < 2; ++mt) {
        int row = m0 + mt * 16 + l16;
        int rowc = (row < nrows) ? row : (nrows - 1);
        const uint4* mrow = (const uint4*)(meanb + (size_t)rowc * 128);
        const uint4* xrow = (const uint4*)(xb + (size_t)rowc * 128);
        bf16x8 af[8];
#pragma unroll
        for (int ks = 0; ks < 4; ++ks) {
            af[ks]     = __builtin_bit_cast(bf16x8, mrow[ks * 4 + quad]);
            af[ks + 4] = __builtin_bit_cast(bf16x8, xrow[ks * 4 + quad]);
        }

        // ---- gemm1 for this m-tile (W1 frags from global) ----
#pragma unroll
        for (int ct = 0; ct < 8; ++ct) {
            f32x4 acc = (f32x4){0.f, 0.f, 0.f, 0.f};
#pragma unroll
            for (int ks = 0; ks < 8; ++ks) {
                bf16x8 bf = __builtin_bit_cast(bf16x8, w1p[(ct * 8 + ks) * 64]);
                acc = __builtin_amdgcn_mfma_f32_16x16x32_bf16(af[ks], bf, acc, 0, 0, 0);
            }
            // epilogue: bias + relu -> bf16 into per-wave LDS scratch (C-layout)
            int col = ct * 16 + l16;
            float bb = b1[col];
#pragma unroll
            for (int r = 0; r < 4; ++r) {
                float v = fmaxf(acc[r] + bb, 0.f);
                hs[wid][(quad * 4 + r) * HSTRIDE + col] = f2bf(v);
            }
        }

        // ---- transpose read: A-frags of h (row = l16, k = ks*32 + quad*8 + j)
        bf16x8 af2[4];
#pragma unroll
        for (int ks = 0; ks < 4; ++ks) {
            uint4 t = *(const uint4*)(hsw + l16 * HSTRIDE + ks * 32 + quad * 8);
            af2[ks] = __builtin_bit_cast(bf16x8, t);
        }

        // ---- gemm2 for this m-tile (W2 from LDS) ----
#pragma unroll
        for (int ct = 0; ct < 8; ++ct) {
            f32x4 acc = (f32x4){0.f, 0.f, 0.f, 0.f};
#pragma unroll
            for (int ks = 0; ks < 4; ++ks) {
                bf16x8 bf = __builtin_bit_cast(bf16x8, sW2[(ct * 4 + ks) * 64 + lane]);
                acc = __builtin_amdgcn_mfma_f32_16x16x32_bf16(af2[ks], bf, acc, 0, 0, 0);
            }
            int col = ct * 16 + l16;
#pragma unroll
            for (int r = 0; r < 4; ++r) {
                int orow = m0 + mt * 16 + quad * 4 + r;
                if (orow < nrows) {
                    if (col < 64) {
                        z2[(size_t)orow * 64 + col] = f2bf(acc[r]);
                    } else {
                        w2out[(size_t)orow * 64 + (col - 64)] = acc[r] + b2[col - 64];
                    }
                }
            }
        }
    }
}

extern "C" void kernel_launch(void* const* d_in, const int* in_sizes, int n_in,
                              void* d_out, int out_size, void* d_ws, size_t ws_size,
                              hipStream_t stream) {
    const float* x    = (const float*)d_in[0];
    const float* W1_l = (const float*)d_in[1];
    const float* b1   = (const float*)d_in[2];
    const float* W1_r = (const float*)d_in[3];
    const float* W2_l = (const float*)d_in[4];
    const float* b2   = (const float*)d_in[5];
    const float* W2_r = (const float*)d_in[6];
    const void*  ei   = d_in[7];
    float* out = (float*)d_out;

    const int N = in_sizes[0] / 128;      // 100000
    const int E = in_sizes[7] / 2;        // 1600000
    const int nbuck = (N + 255) >> 8;     // 391

    // workspace layout
    uintptr_t base = (uintptr_t)d_ws;
    int* flag = (int*)base;                                   // 1 int
    int* bucket_cnt  = (int*)(base + 64);                     // nbuck
    int* bucket_base = bucket_cnt + MAXBUCK;                  // nbuck+1
    int* bucket_pos  = bucket_base + MAXBUCK + 1;             // nbuck
    int* off = (int*)(base + 4096 + 3 * MAXBUCK * 4);
    off = (int*)(((uintptr_t)off + 255) & ~(uintptr_t)255);   // N+1
    int* csr = off + (N + 1);                                 // E
    uintptr_t p = ((uintptr_t)(csr + E) + 255) & ~(uintptr_t)255;
    unsigned short* xb    = (unsigned short*)p; p += (size_t)N * 128 * 2;   // bf16 x (later w2 fp32, same extent)
    unsigned short* meanb = (unsigned short*)p; p += (size_t)N * 128 * 2;   // ebuf / bf16 mean
    unsigned short* hbr   = (unsigned short*)p; p += (size_t)N * 128 * 2;   // z2 region
    uint4* w1frag = (uint4*)p; p += 4096 * 16;
    uint4* w2frag = (uint4*)p; p += 2048 * 16;
    unsigned* ebuf = (unsigned*)meanb;     // dead before agg_mean128_bf writes meanb
    unsigned short* z2 = hbr;              // bf16 N*64
    float* w2 = (float*)xb;                // fp32 N*64; xb dead after gemm12 reads it
                                           // (block-disjoint rows, read-before-write)

    const int* ei32 = (const int*)ei;
    const long long* ei64 = (const long long*)ei;

    detect_zero<<<1, 256, 0, stream>>>(ei, N, flag, bucket_cnt);

    // fused prep: cvt | w1frag | w2frag | coarse hist
    long long n8 = (long long)N * 128 / 8;
    int ncvt = (int)((n8 + 255) / 256);
    prep_kernel<<<ncvt + 16 + 8 + HISTB, 256, 0, stream>>>(
        x, xb, n8, ncvt, W1_l, W1_r, w1frag, W2_l, W2_r, w2frag,
        ei32, ei64, flag, E, nbuck, bucket_cnt);

    bucket_scan<<<1, 256, 0, stream>>>(bucket_cnt, nbuck, bucket_base, bucket_pos);
    int ept = (E + P2B * 256 - 1) / (P2B * 256);   // 13 for E=1.6M (<= MAXEPT)
    pass2_partition<<<P2B, 256, 0, stream>>>(ei32, ei64, flag, E, ept, nbuck,
                                             bucket_pos, ebuf);
    pass3_finalize<<<nbuck, 256, 0, stream>>>(ebuf, bucket_base, nbuck, N, E, off, csr);

    int ablocks = (N + 3) / 4;
    int gblocks = (N + 127) / 128;

    // layer 1 agg
    agg_mean128_bf<<<ablocks, 256, 0, stream>>>(xb, off, csr, meanb, N);
    // fused layer-1 linear + layer-2 linear (h stays on-chip)
    gemm12_mfma<<<gblocks, 256, 0, stream>>>(meanb, xb, w1frag, w2frag, b1, b2,
                                             z2, w2, N);
    // layer 2 agg (commuted) + epilogue
    agg_mean64_bf_ep<<<ablocks, 256, 0, stream>>>(z2, w2, off, csr, out, N);
}